// Round 2
// baseline (3327.381 us; speedup 1.0000x reference)
//
#include <hip/hip_runtime.h>
#include <math.h>

#define NHEADS   64
#define EMB      2048
#define STATE    128
#define KCONV    4
#define HEAD_DIM 64
#define CHUNK    128
#define SEQL     2048
#define NBATCH   2
#define NCH      (SEQL/CHUNK)          // 16
#define INTER    (NHEADS*HEAD_DIM)     // 4096
#define CONVD    (INTER + 2*STATE)     // 4352
#define PROJD    (INTER + CONVD + NHEADS) // 8512
#define ROWS     (NBATCH*SEQL)         // 4096
#define EPSV     1e-6f

__device__ __forceinline__ float sigmoidf_(float x){ return 1.f/(1.f+expf(-x)); }

// ---- bf16 (stored as ushort) helpers, f32 math everywhere -----------------
__device__ __forceinline__ float b2f(ushort u){
  union{float f; unsigned u;} x; x.u = ((unsigned)u)<<16; return x.f;
}
__device__ __forceinline__ ushort f2b(float f){
  union{float f; unsigned u;} x; x.f=f;
  unsigned r = x.u + 0x7FFFu + ((x.u>>16)&1u);
  return (ushort)(r>>16);
}
__device__ __forceinline__ float4 ld4(const float* p){ return *(const float4*)p; }
__device__ __forceinline__ float4 ld4(const ushort* p){
  ushort4 v = *(const ushort4*)p;
  return make_float4(b2f(v.x),b2f(v.y),b2f(v.z),b2f(v.w));
}
__device__ __forceinline__ void st4(float* p, float4 v){ *(float4*)p = v; }
__device__ __forceinline__ void st4(ushort* p, float4 v){
  ushort4 o; o.x=f2b(v.x); o.y=f2b(v.y); o.z=f2b(v.z); o.w=f2b(v.w);
  *(ushort4*)p = o;
}

// ---------------------------------------------------------------------------
// Generic batched NT GEMM: C[m,n] = sum_k A[m,k]*B[n,k], f32 accumulate.
// BM=BN=128, BK=16, 256 threads, 8x8 microtile. N guarded (8512 % 128 != 0).
// ---------------------------------------------------------------------------
#define BM 128
#define BN 128
#define BKK 16

template<typename TA, typename TB, typename TC>
__global__ __launch_bounds__(256) void gemm_bnt(
    const TA* __restrict__ A, int lda, long sA,
    const TB* __restrict__ B, int ldb, long sB,
    TC* __restrict__ C, int ldc, long sC,
    int M, int N, int K)
{
  A += (long)blockIdx.z * sA;
  B += (long)blockIdx.z * sB;
  C += (long)blockIdx.z * sC;
  const int n0 = blockIdx.x * BN;
  const int m0 = blockIdx.y * BM;
  __shared__ float As[BKK][BM+4];
  __shared__ float Bs[BKK][BN+4];
  const int t = threadIdx.x;
  const int tx = t & 15, ty = t >> 4;
  float acc[8][8];
  #pragma unroll
  for (int i=0;i<8;++i)
    #pragma unroll
    for (int j=0;j<8;++j) acc[i][j]=0.f;

  for (int k0 = 0; k0 < K; k0 += BKK) {
    #pragma unroll
    for (int i = 0; i < 2; ++i) {
      int f = t + i*256;
      int row = f >> 2, kq = (f & 3) << 2;
      float4 v = ld4(A + (long)(m0+row)*lda + (k0 + kq));
      As[kq+0][row]=v.x; As[kq+1][row]=v.y; As[kq+2][row]=v.z; As[kq+3][row]=v.w;
      int gn = n0 + row;
      float4 w = make_float4(0.f,0.f,0.f,0.f);
      if (gn < N) w = ld4(B + (long)gn*ldb + (k0 + kq));
      Bs[kq+0][row]=w.x; Bs[kq+1][row]=w.y; Bs[kq+2][row]=w.z; Bs[kq+3][row]=w.w;
    }
    __syncthreads();
    #pragma unroll
    for (int k = 0; k < BKK; ++k) {
      float a[8], b[8];
      *(float4*)&a[0] = *(const float4*)&As[k][ty*8];
      *(float4*)&a[4] = *(const float4*)&As[k][ty*8+4];
      *(float4*)&b[0] = *(const float4*)&Bs[k][tx*8];
      *(float4*)&b[4] = *(const float4*)&Bs[k][tx*8+4];
      #pragma unroll
      for (int i = 0; i < 8; ++i)
        #pragma unroll
        for (int j = 0; j < 8; ++j)
          acc[i][j] = fmaf(a[i], b[j], acc[i][j]);
    }
    __syncthreads();
  }
  #pragma unroll
  for (int i = 0; i < 8; ++i) {
    int gm = m0 + ty*8 + i;
    #pragma unroll
    for (int j = 0; j < 8; j += 4) {
      int gn = n0 + tx*8 + j;
      if (gn < N)
        st4(C + (long)gm*ldc + gn,
            make_float4(acc[i][j],acc[i][j+1],acc[i][j+2],acc[i][j+3]));
    }
  }
}

// ---------------------------------------------------------------------------
// Depthwise causal conv (K=4) + bias + SiLU over proj cols [INTER, INTER+CONVD)
// ---------------------------------------------------------------------------
__global__ __launch_bounds__(256) void conv_silu_kernel(
    const ushort* __restrict__ proj, const float* __restrict__ cw,
    const float* __restrict__ cb, ushort* __restrict__ out)
{
  const int C4 = CONVD/4;
  long idx = (long)blockIdx.x*256 + threadIdx.x;
  if (idx >= (long)ROWS*C4) return;
  int r = (int)(idx / C4);
  int c = (int)(idx % C4) * 4;
  int tt = r & (SEQL-1);
  float4 bv = *(const float4*)(cb + c);
  float acc0=bv.x, acc1=bv.y, acc2=bv.z, acc3=bv.w;
  float4 w0 = *(const float4*)(cw + (c+0)*KCONV);
  float4 w1 = *(const float4*)(cw + (c+1)*KCONV);
  float4 w2 = *(const float4*)(cw + (c+2)*KCONV);
  float4 w3 = *(const float4*)(cw + (c+3)*KCONV);
  const float wj0[4] = {w0.x,w0.y,w0.z,w0.w};
  const float wj1[4] = {w1.x,w1.y,w1.z,w1.w};
  const float wj2[4] = {w2.x,w2.y,w2.z,w2.w};
  const float wj3[4] = {w3.x,w3.y,w3.z,w3.w};
  #pragma unroll
  for (int j = 0; j < KCONV; ++j) {
    int tr = tt - (KCONV-1) + j;
    if (tr >= 0) {
      float4 v = ld4(proj + (long)(r - (KCONV-1) + j)*PROJD + INTER + c);
      acc0 = fmaf(v.x, wj0[j], acc0);
      acc1 = fmaf(v.y, wj1[j], acc1);
      acc2 = fmaf(v.z, wj2[j], acc2);
      acc3 = fmaf(v.w, wj3[j], acc3);
    }
  }
  float4 o;
  o.x = acc0 * sigmoidf_(acc0);
  o.y = acc1 * sigmoidf_(acc1);
  o.z = acc2 * sigmoidf_(acc2);
  o.w = acc3 * sigmoidf_(acc3);
  st4(out + (long)r*CONVD + c, o);
}

// dt = softplus(dt_raw + bias)
__global__ void dt_kernel(const ushort* __restrict__ proj,
                          const float* __restrict__ dt_bias,
                          float* __restrict__ dtb)
{
  int idx = blockIdx.x*256 + threadIdx.x;
  if (idx >= ROWS*NHEADS) return;
  int r = idx >> 6, h = idx & 63;
  float xv = b2f(proj[(long)r*PROJD + INTER + CONVD + h]) + dt_bias[h];
  dtb[idx] = fmaxf(xv, 0.f) + log1pf(expf(-fabsf(xv)));
}

// per-(b,chunk,head) inclusive cumsum of A*dt over the chunk
__global__ void acum_kernel(const float* __restrict__ dtb,
                            const float* __restrict__ A_log,
                            float* __restrict__ acum)
{
  int idx = blockIdx.x*256 + threadIdx.x;
  if (idx >= NBATCH*NCH*NHEADS) return;
  int h = idx & 63, bc = idx >> 6;
  float Ah = -expf(A_log[h]);
  const float* d = dtb + (long)bc*CHUNK*NHEADS + h;
  float* o = acum + (long)idx*CHUNK;
  float acc = 0.f;
  for (int l = 0; l < CHUNK; ++l) { acc = fmaf(Ah, d[l*NHEADS], acc); o[l] = acc; }
}

// states[b,c,h,p,n] = sum_l B[l,n] * exp(Acum[last]-Acum[l]) * dt[l]*hid[l,p]
__global__ __launch_bounds__(256) void states_kernel(
    const ushort* __restrict__ conv, const float* __restrict__ dtb,
    const float* __restrict__ acum, ushort* __restrict__ states)
{
  const int h = blockIdx.x, c = blockIdx.y, b = blockIdx.z;
  const int bc = b*NCH + c;
  __shared__ float hw[CHUNK][HEAD_DIM];
  __shared__ float Bsh[CHUNK][STATE];
  __shared__ float arow[CHUNK];
  const int t = threadIdx.x;
  const float* ac = acum + ((long)bc*NHEADS + h)*CHUNK;
  if (t < CHUNK) arow[t] = ac[t];
  __syncthreads();
  const float alast = arow[CHUNK-1];
  for (int i = t; i < CHUNK*HEAD_DIM/4; i += 256) {
    int l = i >> 4, pq = (i & 15) << 2;
    float4 v = ld4(conv + ((long)(bc*CHUNK+l))*CONVD + h*HEAD_DIM + pq);
    float w = dtb[(long)(bc*CHUNK+l)*NHEADS + h] * expf(alast - arow[l]);
    hw[l][pq+0]=v.x*w; hw[l][pq+1]=v.y*w; hw[l][pq+2]=v.z*w; hw[l][pq+3]=v.w*w;
  }
  for (int i = t; i < CHUNK*STATE/4; i += 256) {
    int l = i >> 5, nq = (i & 31) << 2;
    float4 v = ld4(conv + ((long)(bc*CHUNK+l))*CONVD + INTER + nq);
    *(float4*)&Bsh[l][nq] = v;
  }
  __syncthreads();
  const int p = t >> 2, nq = (t & 3) * 32;
  float acc[32];
  #pragma unroll
  for (int i=0;i<32;++i) acc[i]=0.f;
  for (int l = 0; l < CHUNK; ++l) {
    float hv = hw[l][p];
    #pragma unroll
    for (int i = 0; i < 32; i += 4) {
      float4 bv = *(const float4*)&Bsh[l][nq+i];
      acc[i+0]=fmaf(hv,bv.x,acc[i+0]);
      acc[i+1]=fmaf(hv,bv.y,acc[i+1]);
      acc[i+2]=fmaf(hv,bv.z,acc[i+2]);
      acc[i+3]=fmaf(hv,bv.w,acc[i+3]);
    }
  }
  ushort* so = states + ((long)bc*NHEADS + h)*HEAD_DIM*STATE + p*STATE + nq;
  #pragma unroll
  for (int i = 0; i < 32; i += 4)
    st4(so + i, make_float4(acc[i],acc[i+1],acc[i+2],acc[i+3]));
}

// in-place inter-chunk scan: states[c] <- init_state entering chunk c
__global__ __launch_bounds__(256) void scan_kernel(
    ushort* __restrict__ states, const float* __restrict__ acum)
{
  const int bh = blockIdx.x;          // b*NHEADS + h
  const int b = bh >> 6, h = bh & 63;
  const int t = threadIdx.x;
  float acc[32];
  #pragma unroll
  for (int i=0;i<32;++i) acc[i]=0.f;
  for (int c = 0; c < NCH; ++c) {
    const long bch = ((long)(b*NCH + c)*NHEADS + h);
    float lam = expf(acum[bch*CHUNK + CHUNK-1]);
    ushort* sb = states + bch*HEAD_DIM*STATE;
    #pragma unroll
    for (int i = 0; i < 32; ++i) {
      float v = b2f(sb[t + i*256]);
      sb[t + i*256] = f2b(acc[i]);
      acc[i] = fmaf(acc[i], lam, v);
    }
  }
}

// y = Y_diag + Y_off + D*hid  -> written into proj cols [INTER, INTER+INTER)
__global__ __launch_bounds__(256) void y_kernel(
    const ushort* __restrict__ conv, const float* __restrict__ dtb,
    const float* __restrict__ acum, const float* __restrict__ G,
    const ushort* __restrict__ states, const float* __restrict__ Dp,
    ushort* __restrict__ proj)
{
  const int h = blockIdx.x, c = blockIdx.y, b = blockIdx.z;
  const int bc = b*NCH + c;
  __shared__ float M1[CHUNK][CHUNK+1];      // G, then C
  __shared__ float M2[CHUNK][HEAD_DIM+4];   // hid_raw, then initT, then y-stage
  __shared__ float arow[CHUNK];
  __shared__ float dtr[CHUNK];
  const int t = threadIdx.x;
  const int l = t & 127, ph = t >> 7;
  const long r0 = (long)bc*CHUNK;
  if (t < CHUNK) {
    arow[t] = acum[((long)bc*NHEADS + h)*CHUNK + t];
    dtr[t]  = dtb[(r0 + t)*NHEADS + h];
  }
  const float* Gb = G + (long)bc*CHUNK*CHUNK;
  for (int i = t; i < CHUNK*CHUNK; i += 256) M1[i>>7][i&127] = Gb[i];
  for (int i = t; i < CHUNK*HEAD_DIM; i += 256) {
    int s = i >> 6, p = i & 63;
    M2[s][p] = b2f(conv[(r0+s)*CONVD + h*HEAD_DIM + p]);
  }
  __syncthreads();
  const float al = arow[l];
  const float Dh = Dp[h];
  float accv[32];
  #pragma unroll
  for (int i = 0; i < 32; ++i) accv[i] = Dh * M2[l][ph*32 + i];   // D residual
  for (int s = 0; s < CHUNK; ++s) {
    float w = (s <= l) ? (M1[l][s] * expf(al - arow[s]) * dtr[s]) : 0.f;
    #pragma unroll
    for (int i = 0; i < 32; i += 4) {
      float4 hv = *(const float4*)&M2[s][ph*32 + i];
      accv[i+0] = fmaf(w, hv.x, accv[i+0]);
      accv[i+1] = fmaf(w, hv.y, accv[i+1]);
      accv[i+2] = fmaf(w, hv.z, accv[i+2]);
      accv[i+3] = fmaf(w, hv.w, accv[i+3]);
    }
  }
  __syncthreads();
  for (int i = t; i < CHUNK*CHUNK; i += 256) {
    int ll = i >> 7, n = i & 127;
    M1[ll][n] = b2f(conv[(r0+ll)*CONVD + INTER + STATE + n]);
  }
  const ushort* stb = states + ((long)bc*NHEADS + h)*HEAD_DIM*STATE;
  for (int i = t; i < HEAD_DIM*STATE; i += 256) {
    int p = i >> 7, n = i & 127;
    M2[n][p] = b2f(stb[i]);                  // transposed initT[n][p]
  }
  __syncthreads();
  float acco[32];
  #pragma unroll
  for (int i=0;i<32;++i) acco[i]=0.f;
  for (int n = 0; n < STATE; ++n) {
    float w = M1[l][n];
    #pragma unroll
    for (int i = 0; i < 32; i += 4) {
      float4 iv = *(const float4*)&M2[n][ph*32 + i];
      acco[i+0]=fmaf(w,iv.x,acco[i+0]);
      acco[i+1]=fmaf(w,iv.y,acco[i+1]);
      acco[i+2]=fmaf(w,iv.z,acco[i+2]);
      acco[i+3]=fmaf(w,iv.w,acco[i+3]);
    }
  }
  const float el = expf(al);
  __syncthreads();
  #pragma unroll
  for (int i = 0; i < 32; ++i) M2[l][ph*32+i] = accv[i] + el*acco[i];
  __syncthreads();
  for (int i = t; i < CHUNK*HEAD_DIM/4; i += 256) {
    int ll = i >> 4, pq = (i & 15) << 2;
    float4 v = *(const float4*)&M2[ll][pq];
    st4(proj + (r0+ll)*PROJD + INTER + h*HEAD_DIM + pq, v);
  }
}

// yg = y*silu(gate); rmsnorm; write yn back in place (per row)
__global__ __launch_bounds__(256) void gate_norm_kernel(
    ushort* __restrict__ proj, const float* __restrict__ nw)
{
  const int r = blockIdx.x;
  const int t = threadIdx.x;
  __shared__ float red[256];
  ushort* gate = proj + (long)r*PROJD;
  ushort* y = gate + INTER;
  float vals[16];
  float ss = 0.f;
  #pragma unroll
  for (int k = 0; k < 4; ++k) {
    int j = (t + k*256) * 4;
    float4 g = ld4(gate + j);
    float4 yv = ld4(y + j);
    float v0 = yv.x * g.x * sigmoidf_(g.x);
    float v1 = yv.y * g.y * sigmoidf_(g.y);
    float v2 = yv.z * g.z * sigmoidf_(g.z);
    float v3 = yv.w * g.w * sigmoidf_(g.w);
    vals[k*4+0]=v0; vals[k*4+1]=v1; vals[k*4+2]=v2; vals[k*4+3]=v3;
    ss += v0*v0 + v1*v1 + v2*v2 + v3*v3;
  }
  red[t] = ss;
  __syncthreads();
  for (int sft = 128; sft > 0; sft >>= 1) {
    if (t < sft) red[t] += red[t+sft];
    __syncthreads();
  }
  float scale = rsqrtf(red[0] / (float)INTER + EPSV);
  #pragma unroll
  for (int k = 0; k < 4; ++k) {
    int j = (t + k*256) * 4;
    float4 w = *(const float4*)(nw + j);
    st4(y + j, make_float4(vals[k*4+0]*scale*w.x, vals[k*4+1]*scale*w.y,
                           vals[k*4+2]*scale*w.z, vals[k*4+3]*scale*w.w));
  }
}

extern "C" void kernel_launch(void* const* d_in, const int* in_sizes, int n_in,
                              void* d_out, int out_size, void* d_ws, size_t ws_size,
                              hipStream_t stream) {
  const float* x       = (const float*)d_in[0];
  const float* Wi      = (const float*)d_in[1];
  const float* cw      = (const float*)d_in[2];
  const float* cb      = (const float*)d_in[3];
  const float* dt_bias = (const float*)d_in[4];
  const float* A_log   = (const float*)d_in[5];
  const float* Dp      = (const float*)d_in[6];
  const float* nw      = (const float*)d_in[7];
  const float* Wo      = (const float*)d_in[8];
  float* out = (float*)d_out;

  // workspace layout (bf16 for large buffers): total 143,130,624 bytes
  ushort* projb = (ushort*)d_ws;                               // 4096 x 8512 bf16
  ushort* convb = projb + (size_t)ROWS*PROJD;                  // 4096 x 4352 bf16
  float*  dtb   = (float*)(convb + (size_t)ROWS*CONVD);        // 4096 x 64 f32
  float*  acum  = dtb  + (size_t)ROWS*NHEADS;                  // 2048 x 128 f32
  float*  Gb    = acum + (size_t)NBATCH*NCH*NHEADS*CHUNK;      // 32 x 128 x 128 f32
  ushort* st    = (ushort*)(Gb + (size_t)NBATCH*NCH*CHUNK*CHUNK); // 2048 x 64 x 128 bf16

  size_t need = (size_t)ROWS*PROJD*2 + (size_t)ROWS*CONVD*2
              + (size_t)ROWS*NHEADS*4 + (size_t)NBATCH*NCH*NHEADS*CHUNK*4
              + (size_t)NBATCH*NCH*CHUNK*CHUNK*4
              + (size_t)NBATCH*NCH*NHEADS*HEAD_DIM*STATE*2;
  if (ws_size < need) return;   // diagnostic: absmax-fail (not crash) => ws too small

  // 1. proj = x @ Wi^T   (M=4096, N=8512, K=2048) -> bf16
  gemm_bnt<float,float,ushort><<<dim3((PROJD+BN-1)/BN, ROWS/BM, 1), 256, 0, stream>>>(
      x, EMB, 0, Wi, EMB, 0, projb, PROJD, 0, ROWS, PROJD, EMB);
  // 2. causal depthwise conv + silu -> bf16
  conv_silu_kernel<<<(int)(((long)ROWS*(CONVD/4)+255)/256), 256, 0, stream>>>(
      projb, cw, cb, convb);
  // 3. dt = softplus(...)
  dt_kernel<<<ROWS*NHEADS/256, 256, 0, stream>>>(projb, dt_bias, dtb);
  // 4. chunk cumsums of A*dt
  acum_kernel<<<(NBATCH*NCH*NHEADS+255)/256, 256, 0, stream>>>(dtb, A_log, acum);
  // 5. G[l,s] = sum_n C[l,n]*B[s,n] per (b,chunk)   (head-independent!)
  gemm_bnt<ushort,ushort,float><<<dim3(1,1,NBATCH*NCH), 256, 0, stream>>>(
      convb + INTER + STATE, CONVD, (long)CHUNK*CONVD,
      convb + INTER,         CONVD, (long)CHUNK*CONVD,
      Gb, CHUNK, (long)CHUNK*CHUNK, CHUNK, CHUNK, CHUNK);
  // 6. per-chunk end states -> bf16
  states_kernel<<<dim3(NHEADS, NCH, NBATCH), 256, 0, stream>>>(convb, dtb, acum, st);
  // 7. sequential inter-chunk scan (in place)
  scan_kernel<<<NBATCH*NHEADS, 256, 0, stream>>>(st, acum);
  // 8. y = Y_diag + Y_off + D*hid   (into proj cols [INTER, 2*INTER), bf16)
  y_kernel<<<dim3(NHEADS, NCH, NBATCH), 256, 0, stream>>>(
      convb, dtb, acum, Gb, st, Dp, projb);
  // 9. gating + RMSNorm (in place, bf16)
  gate_norm_kernel<<<ROWS, 256, 0, stream>>>(projb, nw);
  // 10. out = yn @ Wo^T   (M=4096, N=2048, K=4096), A bf16 strided in proj
  gemm_bnt<ushort,float,float><<<dim3(EMB/BN, ROWS/BM, 1), 256, 0, stream>>>(
      projb + INTER, PROJD, 0, Wo, INTER, 0, out, EMB, 0, ROWS, EMB, INTER);
}

// Round 3
// 1059.039 us; speedup vs baseline: 3.1419x; 3.1419x over previous
//
#include <hip/hip_runtime.h>
#include <math.h>

#define NHEADS   64
#define EMB      2048
#define STATE    128
#define KCONV    4
#define HEAD_DIM 64
#define CHUNK    128
#define SEQL     2048
#define NBATCH   2
#define NCH      (SEQL/CHUNK)          // 16
#define INTER    (NHEADS*HEAD_DIM)     // 4096
#define CONVD    (INTER + 2*STATE)     // 4352
#define PROJD    (INTER + CONVD + NHEADS) // 8512
#define ROWS     (NBATCH*SEQL)         // 4096
#define EPSV     1e-6f

__device__ __forceinline__ float sigmoidf_(float x){ return 1.f/(1.f+expf(-x)); }

// ---- bf16 (stored as ushort) helpers, f32 math everywhere -----------------
__device__ __forceinline__ float b2f(ushort u){
  union{float f; unsigned u;} x; x.u = ((unsigned)u)<<16; return x.f;
}
__device__ __forceinline__ ushort f2b(float f){
  union{float f; unsigned u;} x; x.f=f;
  unsigned r = x.u + 0x7FFFu + ((x.u>>16)&1u);
  return (ushort)(r>>16);
}
__device__ __forceinline__ float4 ld4(const float* p){ return *(const float4*)p; }
__device__ __forceinline__ float4 ld4(const ushort* p){
  ushort4 v = *(const ushort4*)p;
  return make_float4(b2f(v.x),b2f(v.y),b2f(v.z),b2f(v.w));
}
__device__ __forceinline__ void st4(float* p, float4 v){ *(float4*)p = v; }
__device__ __forceinline__ void st4(ushort* p, float4 v){
  ushort4 o; o.x=f2b(v.x); o.y=f2b(v.y); o.z=f2b(v.z); o.w=f2b(v.w);
  *(ushort4*)p = o;
}
__device__ __forceinline__ void stc(float* p, float v){ *p = v; }
__device__ __forceinline__ void stc(ushort* p, float v){ *p = f2b(v); }

// ---------------------------------------------------------------------------
// f32 -> bf16 bulk convert (n multiple of 8)
// ---------------------------------------------------------------------------
__global__ __launch_bounds__(256) void f32_to_bf16_kernel(
    const float* __restrict__ in, ushort* __restrict__ out, long n)
{
  long i = ((long)blockIdx.x*256 + threadIdx.x) * 8;
  if (i >= n) return;
  float4 a = *(const float4*)(in + i);
  float4 b = *(const float4*)(in + i + 4);
  st4(out + i, a);
  st4(out + i + 4, b);
}

// ---------------------------------------------------------------------------
// MFMA bf16 NT GEMM (m97 structure): C[m,n] = sum_k A[m,k]*B[n,k]
// 128x128 tile, BK=32, 256 threads = 4 waves, each wave 64x64 (4x4 frags of
// 16x16x32). global_load_lds width-16 staging, 2-barrier K-loop.
// M % 128 == 0 assumed; N guarded (loads clamped, stores masked).
// ---------------------------------------------------------------------------
typedef __attribute__((ext_vector_type(8))) short short8v;   // 8 bf16 = 4 VGPR
typedef __attribute__((ext_vector_type(4))) float float4v;

#define GLL16(g, l) __builtin_amdgcn_global_load_lds( \
    (const __attribute__((address_space(1))) void*)(g), \
    (__attribute__((address_space(3))) void*)(l), 16, 0, 0)

template<typename TC>
__global__ __launch_bounds__(256) void gemm_mfma_bt(
    const ushort* __restrict__ A, int lda,
    const ushort* __restrict__ B, int ldb,
    TC* __restrict__ C, int ldc,
    int N, int K)
{
  __shared__ ushort As[128*32];
  __shared__ ushort Bs[128*32];
  const int t = threadIdx.x;
  const int lt = t & 63, w = t >> 6;
  const int wr = w >> 1, wc = w & 1;
  const int m0 = blockIdx.y * 128, n0 = blockIdx.x * 128;

  float4v acc[4][4];
  #pragma unroll
  for (int i=0;i<4;++i)
    #pragma unroll
    for (int j=0;j<4;++j) acc[i][j] = float4v{0.f,0.f,0.f,0.f};

  const int srow = t >> 2;            // 0..63
  const int scol = (t & 3) * 8;       // k element offset of 16B chunk
  const int bn0 = min(n0 + srow, N-1);
  const int bn1 = min(n0 + 64 + srow, N-1);
  const long aoff0 = (long)(m0 + srow) * lda + scol;
  const long aoff1 = (long)(m0 + 64 + srow) * lda + scol;
  const long boff0 = (long)bn0 * ldb + scol;
  const long boff1 = (long)bn1 * ldb + scol;
  const int lr = lt & 15, lk = (lt >> 4) * 8;

  for (int k0 = 0; k0 < K; k0 += 32) {
    GLL16(A + aoff0 + k0, As + t*8);
    GLL16(A + aoff1 + k0, As + 2048 + t*8);
    GLL16(B + boff0 + k0, Bs + t*8);
    GLL16(B + boff1 + k0, Bs + 2048 + t*8);
    __syncthreads();
    short8v af[4], bf[4];
    #pragma unroll
    for (int i = 0; i < 4; ++i) {
      af[i] = *(const short8v*)(As + (wr*64 + i*16 + lr)*32 + lk);
      bf[i] = *(const short8v*)(Bs + (wc*64 + i*16 + lr)*32 + lk);
    }
    #pragma unroll
    for (int i = 0; i < 4; ++i)
      #pragma unroll
      for (int j = 0; j < 4; ++j)
        acc[i][j] = __builtin_amdgcn_mfma_f32_16x16x32_bf16(af[i], bf[j], acc[i][j], 0, 0, 0);
    __syncthreads();
  }

  const int cr = (lt >> 4) * 4;   // C/D: col=lane&15, row=(lane>>4)*4+reg (m89)
  const int cc = lt & 15;
  #pragma unroll
  for (int i = 0; i < 4; ++i) {
    #pragma unroll
    for (int j = 0; j < 4; ++j) {
      int col = n0 + wc*64 + j*16 + cc;
      if (col < N) {
        #pragma unroll
        for (int r = 0; r < 4; ++r) {
          int row = m0 + wr*64 + i*16 + cr + r;
          stc(C + (long)row*ldc + col, acc[i][j][r]);
        }
      }
    }
  }
}

// ---------------------------------------------------------------------------
// SIMT NT GEMM (kept for the small per-chunk G = C B^T, 32 blocks of 128^3)
// ---------------------------------------------------------------------------
#define BM 128
#define BN 128
#define BKK 16

template<typename TA, typename TB, typename TC>
__global__ __launch_bounds__(256) void gemm_bnt(
    const TA* __restrict__ A, int lda, long sA,
    const TB* __restrict__ B, int ldb, long sB,
    TC* __restrict__ C, int ldc, long sC,
    int M, int N, int K)
{
  A += (long)blockIdx.z * sA;
  B += (long)blockIdx.z * sB;
  C += (long)blockIdx.z * sC;
  const int n0 = blockIdx.x * BN;
  const int m0 = blockIdx.y * BM;
  __shared__ float As[BKK][BM+4];
  __shared__ float Bs[BKK][BN+4];
  const int t = threadIdx.x;
  const int tx = t & 15, ty = t >> 4;
  float acc[8][8];
  #pragma unroll
  for (int i=0;i<8;++i)
    #pragma unroll
    for (int j=0;j<8;++j) acc[i][j]=0.f;

  for (int k0 = 0; k0 < K; k0 += BKK) {
    #pragma unroll
    for (int i = 0; i < 2; ++i) {
      int f = t + i*256;
      int row = f >> 2, kq = (f & 3) << 2;
      float4 v = ld4(A + (long)(m0+row)*lda + (k0 + kq));
      As[kq+0][row]=v.x; As[kq+1][row]=v.y; As[kq+2][row]=v.z; As[kq+3][row]=v.w;
      int gn = n0 + row;
      float4 w = make_float4(0.f,0.f,0.f,0.f);
      if (gn < N) w = ld4(B + (long)gn*ldb + (k0 + kq));
      Bs[kq+0][row]=w.x; Bs[kq+1][row]=w.y; Bs[kq+2][row]=w.z; Bs[kq+3][row]=w.w;
    }
    __syncthreads();
    #pragma unroll
    for (int k = 0; k < BKK; ++k) {
      float a[8], b[8];
      *(float4*)&a[0] = *(const float4*)&As[k][ty*8];
      *(float4*)&a[4] = *(const float4*)&As[k][ty*8+4];
      *(float4*)&b[0] = *(const float4*)&Bs[k][tx*8];
      *(float4*)&b[4] = *(const float4*)&Bs[k][tx*8+4];
      #pragma unroll
      for (int i = 0; i < 8; ++i)
        #pragma unroll
        for (int j = 0; j < 8; ++j)
          acc[i][j] = fmaf(a[i], b[j], acc[i][j]);
    }
    __syncthreads();
  }
  #pragma unroll
  for (int i = 0; i < 8; ++i) {
    int gm = m0 + ty*8 + i;
    #pragma unroll
    for (int j = 0; j < 8; j += 4) {
      int gn = n0 + tx*8 + j;
      if (gn < N)
        st4(C + (long)gm*ldc + gn,
            make_float4(acc[i][j],acc[i][j+1],acc[i][j+2],acc[i][j+3]));
    }
  }
}

// ---------------------------------------------------------------------------
// Depthwise causal conv (K=4) + bias + SiLU over proj cols [INTER, INTER+CONVD)
// ---------------------------------------------------------------------------
__global__ __launch_bounds__(256) void conv_silu_kernel(
    const ushort* __restrict__ proj, const float* __restrict__ cw,
    const float* __restrict__ cb, ushort* __restrict__ out)
{
  const int C4 = CONVD/4;
  long idx = (long)blockIdx.x*256 + threadIdx.x;
  if (idx >= (long)ROWS*C4) return;
  int r = (int)(idx / C4);
  int c = (int)(idx % C4) * 4;
  int tt = r & (SEQL-1);
  float4 bv = *(const float4*)(cb + c);
  float acc0=bv.x, acc1=bv.y, acc2=bv.z, acc3=bv.w;
  float4 w0 = *(const float4*)(cw + (c+0)*KCONV);
  float4 w1 = *(const float4*)(cw + (c+1)*KCONV);
  float4 w2 = *(const float4*)(cw + (c+2)*KCONV);
  float4 w3 = *(const float4*)(cw + (c+3)*KCONV);
  const float wj0[4] = {w0.x,w0.y,w0.z,w0.w};
  const float wj1[4] = {w1.x,w1.y,w1.z,w1.w};
  const float wj2[4] = {w2.x,w2.y,w2.z,w2.w};
  const float wj3[4] = {w3.x,w3.y,w3.z,w3.w};
  #pragma unroll
  for (int j = 0; j < KCONV; ++j) {
    int tr = tt - (KCONV-1) + j;
    if (tr >= 0) {
      float4 v = ld4(proj + (long)(r - (KCONV-1) + j)*PROJD + INTER + c);
      acc0 = fmaf(v.x, wj0[j], acc0);
      acc1 = fmaf(v.y, wj1[j], acc1);
      acc2 = fmaf(v.z, wj2[j], acc2);
      acc3 = fmaf(v.w, wj3[j], acc3);
    }
  }
  float4 o;
  o.x = acc0 * sigmoidf_(acc0);
  o.y = acc1 * sigmoidf_(acc1);
  o.z = acc2 * sigmoidf_(acc2);
  o.w = acc3 * sigmoidf_(acc3);
  st4(out + (long)r*CONVD + c, o);
}

// dt = softplus(dt_raw + bias)
__global__ void dt_kernel(const ushort* __restrict__ proj,
                          const float* __restrict__ dt_bias,
                          float* __restrict__ dtb)
{
  int idx = blockIdx.x*256 + threadIdx.x;
  if (idx >= ROWS*NHEADS) return;
  int r = idx >> 6, h = idx & 63;
  float xv = b2f(proj[(long)r*PROJD + INTER + CONVD + h]) + dt_bias[h];
  dtb[idx] = fmaxf(xv, 0.f) + log1pf(expf(-fabsf(xv)));
}

// per-(b,chunk,head) inclusive cumsum of A*dt over the chunk
__global__ void acum_kernel(const float* __restrict__ dtb,
                            const float* __restrict__ A_log,
                            float* __restrict__ acum)
{
  int idx = blockIdx.x*256 + threadIdx.x;
  if (idx >= NBATCH*NCH*NHEADS) return;
  int h = idx & 63, bc = idx >> 6;
  float Ah = -expf(A_log[h]);
  const float* d = dtb + (long)bc*CHUNK*NHEADS + h;
  float* o = acum + (long)idx*CHUNK;
  float acc = 0.f;
  for (int l = 0; l < CHUNK; ++l) { acc = fmaf(Ah, d[l*NHEADS], acc); o[l] = acc; }
}

// states[b,c,h,p,n] = sum_l B[l,n] * exp(Acum[last]-Acum[l]) * dt[l]*hid[l,p]
__global__ __launch_bounds__(256) void states_kernel(
    const ushort* __restrict__ conv, const float* __restrict__ dtb,
    const float* __restrict__ acum, ushort* __restrict__ states)
{
  const int h = blockIdx.x, c = blockIdx.y, b = blockIdx.z;
  const int bc = b*NCH + c;
  __shared__ float hw[CHUNK][HEAD_DIM];
  __shared__ float Bsh[CHUNK][STATE];
  __shared__ float arow[CHUNK];
  const int t = threadIdx.x;
  const float* ac = acum + ((long)bc*NHEADS + h)*CHUNK;
  if (t < CHUNK) arow[t] = ac[t];
  __syncthreads();
  const float alast = arow[CHUNK-1];
  for (int i = t; i < CHUNK*HEAD_DIM/4; i += 256) {
    int l = i >> 4, pq = (i & 15) << 2;
    float4 v = ld4(conv + ((long)(bc*CHUNK+l))*CONVD + h*HEAD_DIM + pq);
    float w = dtb[(long)(bc*CHUNK+l)*NHEADS + h] * expf(alast - arow[l]);
    hw[l][pq+0]=v.x*w; hw[l][pq+1]=v.y*w; hw[l][pq+2]=v.z*w; hw[l][pq+3]=v.w*w;
  }
  for (int i = t; i < CHUNK*STATE/4; i += 256) {
    int l = i >> 5, nq = (i & 31) << 2;
    float4 v = ld4(conv + ((long)(bc*CHUNK+l))*CONVD + INTER + nq);
    *(float4*)&Bsh[l][nq] = v;
  }
  __syncthreads();
  const int p = t >> 2, nq = (t & 3) * 32;
  float acc[32];
  #pragma unroll
  for (int i=0;i<32;++i) acc[i]=0.f;
  for (int l = 0; l < CHUNK; ++l) {
    float hv = hw[l][p];
    #pragma unroll
    for (int i = 0; i < 32; i += 4) {
      float4 bv = *(const float4*)&Bsh[l][nq+i];
      acc[i+0]=fmaf(hv,bv.x,acc[i+0]);
      acc[i+1]=fmaf(hv,bv.y,acc[i+1]);
      acc[i+2]=fmaf(hv,bv.z,acc[i+2]);
      acc[i+3]=fmaf(hv,bv.w,acc[i+3]);
    }
  }
  ushort* so = states + ((long)bc*NHEADS + h)*HEAD_DIM*STATE + p*STATE + nq;
  #pragma unroll
  for (int i = 0; i < 32; i += 4)
    st4(so + i, make_float4(acc[i],acc[i+1],acc[i+2],acc[i+3]));
}

// in-place inter-chunk scan: states[c] <- init_state entering chunk c
__global__ __launch_bounds__(256) void scan_kernel(
    ushort* __restrict__ states, const float* __restrict__ acum)
{
  const int bh = blockIdx.x;          // b*NHEADS + h
  const int b = bh >> 6, h = bh & 63;
  const int t = threadIdx.x;
  float acc[32];
  #pragma unroll
  for (int i=0;i<32;++i) acc[i]=0.f;
  for (int c = 0; c < NCH; ++c) {
    const long bch = ((long)(b*NCH + c)*NHEADS + h);
    float lam = expf(acum[bch*CHUNK + CHUNK-1]);
    ushort* sb = states + bch*HEAD_DIM*STATE;
    #pragma unroll
    for (int i = 0; i < 32; ++i) {
      float v = b2f(sb[t + i*256]);
      sb[t + i*256] = f2b(acc[i]);
      acc[i] = fmaf(acc[i], lam, v);
    }
  }
}

// y = Y_diag + Y_off + D*hid  -> written into proj cols [INTER, INTER+INTER)
__global__ __launch_bounds__(256) void y_kernel(
    const ushort* __restrict__ conv, const float* __restrict__ dtb,
    const float* __restrict__ acum, const float* __restrict__ G,
    const ushort* __restrict__ states, const float* __restrict__ Dp,
    ushort* __restrict__ proj)
{
  const int h = blockIdx.x, c = blockIdx.y, b = blockIdx.z;
  const int bc = b*NCH + c;
  __shared__ float M1[CHUNK][CHUNK+1];      // G, then C
  __shared__ float M2[CHUNK][HEAD_DIM+4];   // hid_raw, then initT, then y-stage
  __shared__ float arow[CHUNK];
  __shared__ float dtr[CHUNK];
  const int t = threadIdx.x;
  const int l = t & 127, ph = t >> 7;
  const long r0 = (long)bc*CHUNK;
  if (t < CHUNK) {
    arow[t] = acum[((long)bc*NHEADS + h)*CHUNK + t];
    dtr[t]  = dtb[(r0 + t)*NHEADS + h];
  }
  const float* Gb = G + (long)bc*CHUNK*CHUNK;
  for (int i = t; i < CHUNK*CHUNK; i += 256) M1[i>>7][i&127] = Gb[i];
  for (int i = t; i < CHUNK*HEAD_DIM; i += 256) {
    int s = i >> 6, p = i & 63;
    M2[s][p] = b2f(conv[(r0+s)*CONVD + h*HEAD_DIM + p]);
  }
  __syncthreads();
  const float al = arow[l];
  const float Dh = Dp[h];
  float accv[32];
  #pragma unroll
  for (int i = 0; i < 32; ++i) accv[i] = Dh * M2[l][ph*32 + i];   // D residual
  for (int s = 0; s < CHUNK; ++s) {
    float w = (s <= l) ? (M1[l][s] * expf(al - arow[s]) * dtr[s]) : 0.f;
    #pragma unroll
    for (int i = 0; i < 32; i += 4) {
      float4 hv = *(const float4*)&M2[s][ph*32 + i];
      accv[i+0] = fmaf(w, hv.x, accv[i+0]);
      accv[i+1] = fmaf(w, hv.y, accv[i+1]);
      accv[i+2] = fmaf(w, hv.z, accv[i+2]);
      accv[i+3] = fmaf(w, hv.w, accv[i+3]);
    }
  }
  __syncthreads();
  for (int i = t; i < CHUNK*CHUNK; i += 256) {
    int ll = i >> 7, n = i & 127;
    M1[ll][n] = b2f(conv[(r0+ll)*CONVD + INTER + STATE + n]);
  }
  const ushort* stb = states + ((long)bc*NHEADS + h)*HEAD_DIM*STATE;
  for (int i = t; i < HEAD_DIM*STATE; i += 256) {
    int p = i >> 7, n = i & 127;
    M2[n][p] = b2f(stb[i]);                  // transposed initT[n][p]
  }
  __syncthreads();
  float acco[32];
  #pragma unroll
  for (int i=0;i<32;++i) acco[i]=0.f;
  for (int n = 0; n < STATE; ++n) {
    float w = M1[l][n];
    #pragma unroll
    for (int i = 0; i < 32; i += 4) {
      float4 iv = *(const float4*)&M2[n][ph*32 + i];
      acco[i+0]=fmaf(w,iv.x,acco[i+0]);
      acco[i+1]=fmaf(w,iv.y,acco[i+1]);
      acco[i+2]=fmaf(w,iv.z,acco[i+2]);
      acco[i+3]=fmaf(w,iv.w,acco[i+3]);
    }
  }
  const float el = expf(al);
  __syncthreads();
  #pragma unroll
  for (int i = 0; i < 32; ++i) M2[l][ph*32+i] = accv[i] + el*acco[i];
  __syncthreads();
  for (int i = t; i < CHUNK*HEAD_DIM/4; i += 256) {
    int ll = i >> 4, pq = (i & 15) << 2;
    float4 v = *(const float4*)&M2[ll][pq];
    st4(proj + (r0+ll)*PROJD + INTER + h*HEAD_DIM + pq, v);
  }
}

// yg = y*silu(gate); rmsnorm; write yn back in place (per row)
__global__ __launch_bounds__(256) void gate_norm_kernel(
    ushort* __restrict__ proj, const float* __restrict__ nw)
{
  const int r = blockIdx.x;
  const int t = threadIdx.x;
  __shared__ float red[256];
  ushort* gate = proj + (long)r*PROJD;
  ushort* y = gate + INTER;
  float vals[16];
  float ss = 0.f;
  #pragma unroll
  for (int k = 0; k < 4; ++k) {
    int j = (t + k*256) * 4;
    float4 g = ld4(gate + j);
    float4 yv = ld4(y + j);
    float v0 = yv.x * g.x * sigmoidf_(g.x);
    float v1 = yv.y * g.y * sigmoidf_(g.y);
    float v2 = yv.z * g.z * sigmoidf_(g.z);
    float v3 = yv.w * g.w * sigmoidf_(g.w);
    vals[k*4+0]=v0; vals[k*4+1]=v1; vals[k*4+2]=v2; vals[k*4+3]=v3;
    ss += v0*v0 + v1*v1 + v2*v2 + v3*v3;
  }
  red[t] = ss;
  __syncthreads();
  for (int sft = 128; sft > 0; sft >>= 1) {
    if (t < sft) red[t] += red[t+sft];
    __syncthreads();
  }
  float scale = rsqrtf(red[0] / (float)INTER + EPSV);
  #pragma unroll
  for (int k = 0; k < 4; ++k) {
    int j = (t + k*256) * 4;
    float4 w = *(const float4*)(nw + j);
    st4(y + j, make_float4(vals[k*4+0]*scale*w.x, vals[k*4+1]*scale*w.y,
                           vals[k*4+2]*scale*w.z, vals[k*4+3]*scale*w.w));
  }
}

extern "C" void kernel_launch(void* const* d_in, const int* in_sizes, int n_in,
                              void* d_out, int out_size, void* d_ws, size_t ws_size,
                              hipStream_t stream) {
  const float* x       = (const float*)d_in[0];
  const float* Wi      = (const float*)d_in[1];
  const float* cw      = (const float*)d_in[2];
  const float* cb      = (const float*)d_in[3];
  const float* dt_bias = (const float*)d_in[4];
  const float* A_log   = (const float*)d_in[5];
  const float* Dp      = (const float*)d_in[6];
  const float* nw      = (const float*)d_in[7];
  const float* Wo      = (const float*)d_in[8];
  float* out = (float*)d_out;

  // ---- workspace layout: identical 143,130,624-byte footprint as R2 -------
  // projb [4096x8512 bf16] | region R:
  //   phase A (pre-GEMM1):  xb [4096x2048 bf16] Wib [8512x2048 bf16]
  //   phase B (SSM core):   convb dtb acum Gb st
  //   phase C (post-y):     Wob [2048x4096 bf16] overlays dead convb
  ushort* projb = (ushort*)d_ws;
  ushort* R     = projb + (size_t)ROWS*PROJD;
  ushort* xb    = R;
  ushort* Wib   = R + (size_t)ROWS*EMB;
  ushort* Wob   = R;
  ushort* convb = R;
  float*  dtb   = (float*)(convb + (size_t)ROWS*CONVD);
  float*  acum  = dtb  + (size_t)ROWS*NHEADS;
  float*  Gb    = acum + (size_t)NBATCH*NCH*NHEADS*CHUNK;
  ushort* st    = (ushort*)(Gb + (size_t)NBATCH*NCH*CHUNK*CHUNK);

  size_t need = (size_t)ROWS*PROJD*2 + (size_t)ROWS*CONVD*2
              + (size_t)ROWS*NHEADS*4 + (size_t)NBATCH*NCH*NHEADS*CHUNK*4
              + (size_t)NBATCH*NCH*CHUNK*CHUNK*4
              + (size_t)NBATCH*NCH*NHEADS*HEAD_DIM*STATE*2;
  if (ws_size < need) return;

  // 0. convert x, Wi to bf16
  f32_to_bf16_kernel<<<(int)((long)ROWS*EMB/8/256), 256, 0, stream>>>(x, xb, (long)ROWS*EMB);
  f32_to_bf16_kernel<<<(int)((long)PROJD*EMB/8/256), 256, 0, stream>>>(Wi, Wib, (long)PROJD*EMB);
  // 1. proj = x @ Wi^T  (MFMA, M=4096, N=8512, K=2048) -> bf16
  gemm_mfma_bt<ushort><<<dim3((PROJD+127)/128, ROWS/128), 256, 0, stream>>>(
      xb, EMB, Wib, EMB, projb, PROJD, PROJD, EMB);
  // 2. causal depthwise conv + silu -> bf16 (overwrites xb/Wib: dead)
  conv_silu_kernel<<<(int)(((long)ROWS*(CONVD/4)+255)/256), 256, 0, stream>>>(
      projb, cw, cb, convb);
  // 3. dt = softplus(...)
  dt_kernel<<<ROWS*NHEADS/256, 256, 0, stream>>>(projb, dt_bias, dtb);
  // 4. chunk cumsums of A*dt
  acum_kernel<<<(NBATCH*NCH*NHEADS+255)/256, 256, 0, stream>>>(dtb, A_log, acum);
  // 5. G[l,s] = sum_n C[l,n]*B[s,n] per (b,chunk)
  gemm_bnt<ushort,ushort,float><<<dim3(1,1,NBATCH*NCH), 256, 0, stream>>>(
      convb + INTER + STATE, CONVD, (long)CHUNK*CONVD,
      convb + INTER,         CONVD, (long)CHUNK*CONVD,
      Gb, CHUNK, (long)CHUNK*CHUNK, CHUNK, CHUNK, CHUNK);
  // 6. per-chunk end states -> bf16
  states_kernel<<<dim3(NHEADS, NCH, NBATCH), 256, 0, stream>>>(convb, dtb, acum, st);
  // 7. sequential inter-chunk scan (in place)
  scan_kernel<<<NBATCH*NHEADS, 256, 0, stream>>>(st, acum);
  // 8. y = Y_diag + Y_off + D*hid  (into proj cols [INTER, 2*INTER), bf16)
  y_kernel<<<dim3(NHEADS, NCH, NBATCH), 256, 0, stream>>>(
      convb, dtb, acum, Gb, st, Dp, projb);
  // 9. gating + RMSNorm (in place, bf16)
  gate_norm_kernel<<<ROWS, 256, 0, stream>>>(projb, nw);
  // 9.5 convert Wo to bf16 (overlays dead convb — after y_kernel)
  f32_to_bf16_kernel<<<(int)((long)EMB*INTER/8/256), 256, 0, stream>>>(Wo, Wob, (long)EMB*INTER);
  // 10. out = yn @ Wo^T  (MFMA, M=4096, N=2048, K=4096) -> f32
  gemm_mfma_bt<float><<<dim3(EMB/128, ROWS/128), 256, 0, stream>>>(
      projb + INTER, PROJD, Wob, INTER, out, EMB, EMB, INTER);
}

// Round 5
// 807.242 us; speedup vs baseline: 4.1219x; 1.3119x over previous
//
#include <hip/hip_runtime.h>
#include <math.h>

#define NHEADS   64
#define EMB      2048
#define STATE    128
#define KCONV    4
#define HEAD_DIM 64
#define CHUNK    128
#define SEQL     2048
#define NBATCH   2
#define NCH      (SEQL/CHUNK)          // 16
#define INTER    (NHEADS*HEAD_DIM)     // 4096
#define CONVD    (INTER + 2*STATE)     // 4352
#define PROJD    (INTER + CONVD + NHEADS) // 8512
#define ROWS     (NBATCH*SEQL)         // 4096
#define EPSV     1e-6f

__device__ __forceinline__ float sigmoidf_(float x){ return 1.f/(1.f+expf(-x)); }

// ---- bf16 (stored as ushort) helpers, f32 math everywhere -----------------
__device__ __forceinline__ float b2f(ushort u){
  union{float f; unsigned u;} x; x.u = ((unsigned)u)<<16; return x.f;
}
__device__ __forceinline__ ushort f2b(float f){
  union{float f; unsigned u;} x; x.f=f;
  unsigned r = x.u + 0x7FFFu + ((x.u>>16)&1u);
  return (ushort)(r>>16);
}
__device__ __forceinline__ float4 ld4(const float* p){ return *(const float4*)p; }
__device__ __forceinline__ float4 ld4(const ushort* p){
  ushort4 v = *(const ushort4*)p;
  return make_float4(b2f(v.x),b2f(v.y),b2f(v.z),b2f(v.w));
}
__device__ __forceinline__ void st4(float* p, float4 v){ *(float4*)p = v; }
__device__ __forceinline__ void st4(ushort* p, float4 v){
  ushort4 o; o.x=f2b(v.x); o.y=f2b(v.y); o.z=f2b(v.z); o.w=f2b(v.w);
  *(ushort4*)p = o;
}
__device__ __forceinline__ void stc(float* p, float v){ *p = v; }
__device__ __forceinline__ void stc(ushort* p, float v){ *p = f2b(v); }

// ---------------------------------------------------------------------------
// f32 -> bf16 bulk convert (n multiple of 8)
// ---------------------------------------------------------------------------
__global__ __launch_bounds__(256) void f32_to_bf16_kernel(
    const float* __restrict__ in, ushort* __restrict__ out, long n)
{
  long i = ((long)blockIdx.x*256 + threadIdx.x) * 8;
  if (i >= n) return;
  float4 a = *(const float4*)(in + i);
  float4 b = *(const float4*)(in + i + 4);
  st4(out + i, a);
  st4(out + i + 4, b);
}

// ---------------------------------------------------------------------------
// MFMA bf16 NT GEMM (m97 structure): C[m,n] = sum_k A[m,k]*B[n,k]
// 128x128 tile, BK=32, 256 threads = 4 waves, each wave 64x64 (4x4 frags of
// 16x16x32). global_load_lds width-16 staging, 2-barrier K-loop.
// M % 128 == 0 assumed; N guarded (loads clamped, stores masked).
// ---------------------------------------------------------------------------
typedef __attribute__((ext_vector_type(8))) short short8v;   // 8 bf16 = 4 VGPR
typedef __attribute__((ext_vector_type(4))) float float4v;

#define GLL16(g, l) __builtin_amdgcn_global_load_lds( \
    (const __attribute__((address_space(1))) void*)(g), \
    (__attribute__((address_space(3))) void*)(l), 16, 0, 0)

template<typename TC>
__global__ __launch_bounds__(256) void gemm_mfma_bt(
    const ushort* __restrict__ A, int lda,
    const ushort* __restrict__ B, int ldb,
    TC* __restrict__ C, int ldc,
    int N, int K)
{
  __shared__ ushort As[128*32];
  __shared__ ushort Bs[128*32];
  const int t = threadIdx.x;
  const int lt = t & 63, w = t >> 6;
  const int wr = w >> 1, wc = w & 1;
  const int m0 = blockIdx.y * 128, n0 = blockIdx.x * 128;

  float4v acc[4][4];
  #pragma unroll
  for (int i=0;i<4;++i)
    #pragma unroll
    for (int j=0;j<4;++j) acc[i][j] = float4v{0.f,0.f,0.f,0.f};

  const int srow = t >> 2;            // 0..63
  const int scol = (t & 3) * 8;       // k element offset of 16B chunk
  const int bn0 = min(n0 + srow, N-1);
  const int bn1 = min(n0 + 64 + srow, N-1);
  const long aoff0 = (long)(m0 + srow) * lda + scol;
  const long aoff1 = (long)(m0 + 64 + srow) * lda + scol;
  const long boff0 = (long)bn0 * ldb + scol;
  const long boff1 = (long)bn1 * ldb + scol;
  const int lr = lt & 15, lk = (lt >> 4) * 8;

  for (int k0 = 0; k0 < K; k0 += 32) {
    GLL16(A + aoff0 + k0, As + t*8);
    GLL16(A + aoff1 + k0, As + 2048 + t*8);
    GLL16(B + boff0 + k0, Bs + t*8);
    GLL16(B + boff1 + k0, Bs + 2048 + t*8);
    __syncthreads();
    short8v af[4], bf[4];
    #pragma unroll
    for (int i = 0; i < 4; ++i) {
      af[i] = *(const short8v*)(As + (wr*64 + i*16 + lr)*32 + lk);
      bf[i] = *(const short8v*)(Bs + (wc*64 + i*16 + lr)*32 + lk);
    }
    #pragma unroll
    for (int i = 0; i < 4; ++i)
      #pragma unroll
      for (int j = 0; j < 4; ++j)
        acc[i][j] = __builtin_amdgcn_mfma_f32_16x16x32_bf16(af[i], bf[j], acc[i][j], 0, 0, 0);
    __syncthreads();
  }

  const int cr = (lt >> 4) * 4;   // C/D: col=lane&15, row=(lane>>4)*4+reg (m89)
  const int cc = lt & 15;
  #pragma unroll
  for (int i = 0; i < 4; ++i) {
    #pragma unroll
    for (int j = 0; j < 4; ++j) {
      int col = n0 + wc*64 + j*16 + cc;
      if (col < N) {
        #pragma unroll
        for (int r = 0; r < 4; ++r) {
          int row = m0 + wr*64 + i*16 + cr + r;
          stc(C + (long)row*ldc + col, acc[i][j][r]);
        }
      }
    }
  }
}

// ---------------------------------------------------------------------------
// SIMT NT GEMM (kept for the small per-chunk G = C B^T, 32 blocks of 128^3)
// ---------------------------------------------------------------------------
#define BM 128
#define BN 128
#define BKK 16

template<typename TA, typename TB, typename TC>
__global__ __launch_bounds__(256) void gemm_bnt(
    const TA* __restrict__ A, int lda, long sA,
    const TB* __restrict__ B, int ldb, long sB,
    TC* __restrict__ C, int ldc, long sC,
    int M, int N, int K)
{
  A += (long)blockIdx.z * sA;
  B += (long)blockIdx.z * sB;
  C += (long)blockIdx.z * sC;
  const int n0 = blockIdx.x * BN;
  const int m0 = blockIdx.y * BM;
  __shared__ float As[BKK][BM+4];
  __shared__ float Bs[BKK][BN+4];
  const int t = threadIdx.x;
  const int tx = t & 15, ty = t >> 4;
  float acc[8][8];
  #pragma unroll
  for (int i=0;i<8;++i)
    #pragma unroll
    for (int j=0;j<8;++j) acc[i][j]=0.f;

  for (int k0 = 0; k0 < K; k0 += BKK) {
    #pragma unroll
    for (int i = 0; i < 2; ++i) {
      int f = t + i*256;
      int row = f >> 2, kq = (f & 3) << 2;
      float4 v = ld4(A + (long)(m0+row)*lda + (k0 + kq));
      As[kq+0][row]=v.x; As[kq+1][row]=v.y; As[kq+2][row]=v.z; As[kq+3][row]=v.w;
      int gn = n0 + row;
      float4 w = make_float4(0.f,0.f,0.f,0.f);
      if (gn < N) w = ld4(B + (long)gn*ldb + (k0 + kq));
      Bs[kq+0][row]=w.x; Bs[kq+1][row]=w.y; Bs[kq+2][row]=w.z; Bs[kq+3][row]=w.w;
    }
    __syncthreads();
    #pragma unroll
    for (int k = 0; k < BKK; ++k) {
      float a[8], b[8];
      *(float4*)&a[0] = *(const float4*)&As[k][ty*8];
      *(float4*)&a[4] = *(const float4*)&As[k][ty*8+4];
      *(float4*)&b[0] = *(const float4*)&Bs[k][tx*8];
      *(float4*)&b[4] = *(const float4*)&Bs[k][tx*8+4];
      #pragma unroll
      for (int i = 0; i < 8; ++i)
        #pragma unroll
        for (int j = 0; j < 8; ++j)
          acc[i][j] = fmaf(a[i], b[j], acc[i][j]);
    }
    __syncthreads();
  }
  #pragma unroll
  for (int i = 0; i < 8; ++i) {
    int gm = m0 + ty*8 + i;
    #pragma unroll
    for (int j = 0; j < 8; j += 4) {
      int gn = n0 + tx*8 + j;
      if (gn < N)
        st4(C + (long)gm*ldc + gn,
            make_float4(acc[i][j],acc[i][j+1],acc[i][j+2],acc[i][j+3]));
    }
  }
}

// ---------------------------------------------------------------------------
// Depthwise causal conv (K=4) + bias + SiLU over proj cols [INTER, INTER+CONVD)
// ---------------------------------------------------------------------------
__global__ __launch_bounds__(256) void conv_silu_kernel(
    const ushort* __restrict__ proj, const float* __restrict__ cw,
    const float* __restrict__ cb, ushort* __restrict__ out)
{
  const int C4 = CONVD/4;
  long idx = (long)blockIdx.x*256 + threadIdx.x;
  if (idx >= (long)ROWS*C4) return;
  int r = (int)(idx / C4);
  int c = (int)(idx % C4) * 4;
  int tt = r & (SEQL-1);
  float4 bv = *(const float4*)(cb + c);
  float acc0=bv.x, acc1=bv.y, acc2=bv.z, acc3=bv.w;
  float4 w0 = *(const float4*)(cw + (c+0)*KCONV);
  float4 w1 = *(const float4*)(cw + (c+1)*KCONV);
  float4 w2 = *(const float4*)(cw + (c+2)*KCONV);
  float4 w3 = *(const float4*)(cw + (c+3)*KCONV);
  const float wj0[4] = {w0.x,w0.y,w0.z,w0.w};
  const float wj1[4] = {w1.x,w1.y,w1.z,w1.w};
  const float wj2[4] = {w2.x,w2.y,w2.z,w2.w};
  const float wj3[4] = {w3.x,w3.y,w3.z,w3.w};
  #pragma unroll
  for (int j = 0; j < KCONV; ++j) {
    int tr = tt - (KCONV-1) + j;
    if (tr >= 0) {
      float4 v = ld4(proj + (long)(r - (KCONV-1) + j)*PROJD + INTER + c);
      acc0 = fmaf(v.x, wj0[j], acc0);
      acc1 = fmaf(v.y, wj1[j], acc1);
      acc2 = fmaf(v.z, wj2[j], acc2);
      acc3 = fmaf(v.w, wj3[j], acc3);
    }
  }
  float4 o;
  o.x = acc0 * sigmoidf_(acc0);
  o.y = acc1 * sigmoidf_(acc1);
  o.z = acc2 * sigmoidf_(acc2);
  o.w = acc3 * sigmoidf_(acc3);
  st4(out + (long)r*CONVD + c, o);
}

// dt = softplus(dt_raw + bias)
__global__ void dt_kernel(const ushort* __restrict__ proj,
                          const float* __restrict__ dt_bias,
                          float* __restrict__ dtb)
{
  int idx = blockIdx.x*256 + threadIdx.x;
  if (idx >= ROWS*NHEADS) return;
  int r = idx >> 6, h = idx & 63;
  float xv = b2f(proj[(long)r*PROJD + INTER + CONVD + h]) + dt_bias[h];
  dtb[idx] = fmaxf(xv, 0.f) + log1pf(expf(-fabsf(xv)));
}

// per-(b,chunk,head) inclusive cumsum of A*dt over the chunk
__global__ void acum_kernel(const float* __restrict__ dtb,
                            const float* __restrict__ A_log,
                            float* __restrict__ acum)
{
  int idx = blockIdx.x*256 + threadIdx.x;
  if (idx >= NBATCH*NCH*NHEADS) return;
  int h = idx & 63, bc = idx >> 6;
  float Ah = -expf(A_log[h]);
  const float* d = dtb + (long)bc*CHUNK*NHEADS + h;
  float* o = acum + (long)idx*CHUNK;
  float acc = 0.f;
  for (int l = 0; l < CHUNK; ++l) { acc = fmaf(Ah, d[l*NHEADS], acc); o[l] = acc; }
}

// states[b,c,h,p,n] = sum_l B[l,n] * exp(Acum[last]-Acum[l]) * dt[l]*hid[l,p]
__global__ __launch_bounds__(256) void states_kernel(
    const ushort* __restrict__ conv, const float* __restrict__ dtb,
    const float* __restrict__ acum, ushort* __restrict__ states)
{
  const int h = blockIdx.x, c = blockIdx.y, b = blockIdx.z;
  const int bc = b*NCH + c;
  __shared__ float hw[CHUNK][HEAD_DIM];
  __shared__ float Bsh[CHUNK][STATE];
  __shared__ float arow[CHUNK];
  const int t = threadIdx.x;
  const float* ac = acum + ((long)bc*NHEADS + h)*CHUNK;
  if (t < CHUNK) arow[t] = ac[t];
  __syncthreads();
  const float alast = arow[CHUNK-1];
  for (int i = t; i < CHUNK*HEAD_DIM/4; i += 256) {
    int l = i >> 4, pq = (i & 15) << 2;
    float4 v = ld4(conv + ((long)(bc*CHUNK+l))*CONVD + h*HEAD_DIM + pq);
    float w = dtb[(long)(bc*CHUNK+l)*NHEADS + h] * expf(alast - arow[l]);
    hw[l][pq+0]=v.x*w; hw[l][pq+1]=v.y*w; hw[l][pq+2]=v.z*w; hw[l][pq+3]=v.w*w;
  }
  for (int i = t; i < CHUNK*STATE/4; i += 256) {
    int l = i >> 5, nq = (i & 31) << 2;
    float4 v = ld4(conv + ((long)(bc*CHUNK+l))*CONVD + INTER + nq);
    *(float4*)&Bsh[l][nq] = v;
  }
  __syncthreads();
  const int p = t >> 2, nq = (t & 3) * 32;
  float acc[32];
  #pragma unroll
  for (int i=0;i<32;++i) acc[i]=0.f;
  for (int l = 0; l < CHUNK; ++l) {
    float hv = hw[l][p];
    #pragma unroll
    for (int i = 0; i < 32; i += 4) {
      float4 bv = *(const float4*)&Bsh[l][nq+i];
      acc[i+0]=fmaf(hv,bv.x,acc[i+0]);
      acc[i+1]=fmaf(hv,bv.y,acc[i+1]);
      acc[i+2]=fmaf(hv,bv.z,acc[i+2]);
      acc[i+3]=fmaf(hv,bv.w,acc[i+3]);
    }
  }
  ushort* so = states + ((long)bc*NHEADS + h)*HEAD_DIM*STATE + p*STATE + nq;
  #pragma unroll
  for (int i = 0; i < 32; i += 4)
    st4(so + i, make_float4(acc[i],acc[i+1],acc[i+2],acc[i+3]));
}

// in-place inter-chunk scan: states[c] <- init_state entering chunk c
__global__ __launch_bounds__(256) void scan_kernel(
    ushort* __restrict__ states, const float* __restrict__ acum)
{
  const int bh = blockIdx.x;          // b*NHEADS + h
  const int b = bh >> 6, h = bh & 63;
  const int t = threadIdx.x;
  float acc[32];
  #pragma unroll
  for (int i=0;i<32;++i) acc[i]=0.f;
  for (int c = 0; c < NCH; ++c) {
    const long bch = ((long)(b*NCH + c)*NHEADS + h);
    float lam = expf(acum[bch*CHUNK + CHUNK-1]);
    ushort* sb = states + bch*HEAD_DIM*STATE;
    #pragma unroll
    for (int i = 0; i < 32; ++i) {
      float v = b2f(sb[t + i*256]);
      sb[t + i*256] = f2b(acc[i]);
      acc[i] = fmaf(acc[i], lam, v);
    }
  }
}

// ---------------------------------------------------------------------------
// MFMA y-kernel: per (h, chunk-half, b):
//   Y[l,p] = sum_s W[l,s]*hid[s,p]  +  exp(al)*sum_n C[l,n]*init[p,n] + D*hid[l,p]
// W staged f32, split hi/lo bf16 on the fly (no added rounding). C used as its
// exact bf16 value; exp(al) applied to the accumulator at epilogue.
// M=64 (half chunk), N=64, K=128 twice. 4 waves, each 16 rows x 64 cols.
// ---------------------------------------------------------------------------
__global__ __launch_bounds__(256) void y_mfma_kernel(
    const ushort* __restrict__ conv, const float* __restrict__ dtb,
    const float* __restrict__ acum, const float* __restrict__ G,
    const ushort* __restrict__ states, const float* __restrict__ Dp,
    ushort* __restrict__ proj)
{
  const int h = blockIdx.x;
  const int c = blockIdx.y >> 1, mh = blockIdx.y & 1;
  const int b = blockIdx.z;
  const int bc = b*NCH + c;
  const int mbase = mh * 64;
  const long r0 = (long)bc*CHUNK;

  __shared__ float  Af[64][132];     // W (f32), then C (f32 from bf16, exact)
  __shared__ ushort B0[64][136];     // hid^T: B0[p][s], s over FULL chunk
  __shared__ ushort B1[64][136];     // init:  B1[p][n] (states row-major copy)
  __shared__ float arow[CHUNK];
  __shared__ float dtr[CHUNK];
  __shared__ float el[64];

  const int t = threadIdx.x;
  const int lt = t & 63, w = t >> 6;       // wave w owns rows w*16..w*16+15
  const int lr = lt & 15, lk = (lt >> 4) * 8;

  if (t < CHUNK) {
    arow[t] = acum[((long)bc*NHEADS + h)*CHUNK + t];
    dtr[t]  = dtb[(r0 + t)*NHEADS + h];
  }
  __syncthreads();

  if (t < 64) el[t] = expf(arow[mbase + t]);
  // B0 = hid^T (transpose on write)
  for (int i = t; i < CHUNK*HEAD_DIM/8; i += 256) {
    int s = i >> 3, p0 = (i & 7) * 8;
    short8v v = *(const short8v*)(conv + (r0+s)*CONVD + h*HEAD_DIM + p0);
    #pragma unroll
    for (int j = 0; j < 8; ++j) B0[p0+j][s] = (ushort)v[j];
  }
  // B1 = init states (direct copy, already [p][n] k-major)
  {
    const ushort* stb = states + ((long)bc*NHEADS + h)*HEAD_DIM*STATE;
    for (int i = t; i < HEAD_DIM*STATE/8; i += 256) {
      int p = i >> 4, n0 = (i & 15) * 8;
      *(short8v*)&B1[p][n0] = *(const short8v*)(stb + p*STATE + n0);
    }
  }
  // A = W (f32)
  {
    const float* Gb = G + (long)bc*CHUNK*CHUNK;
    for (int i = t; i < 64*CHUNK; i += 256) {
      int ll = i >> 7, s = i & 127;
      int l = mbase + ll;
      float wv = 0.f;
      if (s <= l) wv = Gb[l*CHUNK + s] * expf(arow[l] - arow[s]) * dtr[s];
      Af[ll][s] = wv;
    }
  }
  __syncthreads();

  float4v acc1[4], acc2[4];
  #pragma unroll
  for (int j = 0; j < 4; ++j) { acc1[j] = float4v{0,0,0,0}; acc2[j] = float4v{0,0,0,0}; }

  // mm1: Y_diag, W split hi/lo
  #pragma unroll
  for (int kk = 0; kk < 4; ++kk) {
    const float* ap = &Af[w*16 + lr][kk*32 + lk];
    float a8[8];
    *(float4*)&a8[0] = *(const float4*)ap;
    *(float4*)&a8[4] = *(const float4*)(ap + 4);
    short8v ahi, alo;
    #pragma unroll
    for (int e = 0; e < 8; ++e) {
      ushort hb = f2b(a8[e]);
      float rem = a8[e] - b2f(hb);
      ahi[e] = (short)hb;
      alo[e] = (short)f2b(rem);
    }
    #pragma unroll
    for (int nj = 0; nj < 4; ++nj) {
      short8v bfv = *(const short8v*)&B0[nj*16 + lr][kk*32 + lk];
      acc1[nj] = __builtin_amdgcn_mfma_f32_16x16x32_bf16(ahi, bfv, acc1[nj], 0, 0, 0);
      acc1[nj] = __builtin_amdgcn_mfma_f32_16x16x32_bf16(alo, bfv, acc1[nj], 0, 0, 0);
    }
  }
  __syncthreads();

  // A = C (exact bf16 values, staged f32)
  for (int i = t; i < 64*STATE; i += 256) {
    int ll = i >> 7, n = i & 127;
    Af[ll][n] = b2f(conv[(r0 + mbase + ll)*CONVD + INTER + STATE + n]);
  }
  __syncthreads();

  // mm2: C @ init^T (hi only — exact)
  #pragma unroll
  for (int kk = 0; kk < 4; ++kk) {
    const float* ap = &Af[w*16 + lr][kk*32 + lk];
    float a8[8];
    *(float4*)&a8[0] = *(const float4*)ap;
    *(float4*)&a8[4] = *(const float4*)(ap + 4);
    short8v ahi;
    #pragma unroll
    for (int e = 0; e < 8; ++e) ahi[e] = (short)f2b(a8[e]);
    #pragma unroll
    for (int nj = 0; nj < 4; ++nj) {
      short8v bfv = *(const short8v*)&B1[nj*16 + lr][kk*32 + lk];
      acc2[nj] = __builtin_amdgcn_mfma_f32_16x16x32_bf16(ahi, bfv, acc2[nj], 0, 0, 0);
    }
  }

  // epilogue: y = acc1 + el*acc2 + D*hid ; store bf16 into proj y-slot
  const float Dh = Dp[h];
  const int cr = (lt >> 4) * 4, cc = lt & 15;
  #pragma unroll
  for (int nj = 0; nj < 4; ++nj) {
    int p = nj*16 + cc;
    #pragma unroll
    for (int r = 0; r < 4; ++r) {
      int ll = w*16 + cr + r;
      float hid_raw = b2f(B0[p][mbase + ll]);   // FIX: hid at chunk pos mbase+ll
      float yv = acc1[nj][r] + el[ll]*acc2[nj][r] + Dh*hid_raw;
      proj[(r0 + mbase + ll)*PROJD + INTER + h*HEAD_DIM + p] = f2b(yv);
    }
  }
}

// yg = y*silu(gate); rmsnorm; write yn back in place (per row)
__global__ __launch_bounds__(256) void gate_norm_kernel(
    ushort* __restrict__ proj, const float* __restrict__ nw)
{
  const int r = blockIdx.x;
  const int t = threadIdx.x;
  __shared__ float red[256];
  ushort* gate = proj + (long)r*PROJD;
  ushort* y = gate + INTER;
  float vals[16];
  float ss = 0.f;
  #pragma unroll
  for (int k = 0; k < 4; ++k) {
    int j = (t + k*256) * 4;
    float4 g = ld4(gate + j);
    float4 yv = ld4(y + j);
    float v0 = yv.x * g.x * sigmoidf_(g.x);
    float v1 = yv.y * g.y * sigmoidf_(g.y);
    float v2 = yv.z * g.z * sigmoidf_(g.z);
    float v3 = yv.w * g.w * sigmoidf_(g.w);
    vals[k*4+0]=v0; vals[k*4+1]=v1; vals[k*4+2]=v2; vals[k*4+3]=v3;
    ss += v0*v0 + v1*v1 + v2*v2 + v3*v3;
  }
  red[t] = ss;
  __syncthreads();
  for (int sft = 128; sft > 0; sft >>= 1) {
    if (t < sft) red[t] += red[t+sft];
    __syncthreads();
  }
  float scale = rsqrtf(red[0] / (float)INTER + EPSV);
  #pragma unroll
  for (int k = 0; k < 4; ++k) {
    int j = (t + k*256) * 4;
    float4 w = *(const float4*)(nw + j);
    st4(y + j, make_float4(vals[k*4+0]*scale*w.x, vals[k*4+1]*scale*w.y,
                           vals[k*4+2]*scale*w.z, vals[k*4+3]*scale*w.w));
  }
}

extern "C" void kernel_launch(void* const* d_in, const int* in_sizes, int n_in,
                              void* d_out, int out_size, void* d_ws, size_t ws_size,
                              hipStream_t stream) {
  const float* x       = (const float*)d_in[0];
  const float* Wi      = (const float*)d_in[1];
  const float* cw      = (const float*)d_in[2];
  const float* cb      = (const float*)d_in[3];
  const float* dt_bias = (const float*)d_in[4];
  const float* A_log   = (const float*)d_in[5];
  const float* Dp      = (const float*)d_in[6];
  const float* nw      = (const float*)d_in[7];
  const float* Wo      = (const float*)d_in[8];
  float* out = (float*)d_out;

  // ---- workspace layout: identical 143,130,624-byte footprint as R2 -------
  ushort* projb = (ushort*)d_ws;
  ushort* R     = projb + (size_t)ROWS*PROJD;
  ushort* xb    = R;
  ushort* Wib   = R + (size_t)ROWS*EMB;
  ushort* Wob   = R;
  ushort* convb = R;
  float*  dtb   = (float*)(convb + (size_t)ROWS*CONVD);
  float*  acum  = dtb  + (size_t)ROWS*NHEADS;
  float*  Gb    = acum + (size_t)NBATCH*NCH*NHEADS*CHUNK;
  ushort* st    = (ushort*)(Gb + (size_t)NBATCH*NCH*CHUNK*CHUNK);

  size_t need = (size_t)ROWS*PROJD*2 + (size_t)ROWS*CONVD*2
              + (size_t)ROWS*NHEADS*4 + (size_t)NBATCH*NCH*NHEADS*CHUNK*4
              + (size_t)NBATCH*NCH*CHUNK*CHUNK*4
              + (size_t)NBATCH*NCH*NHEADS*HEAD_DIM*STATE*2;
  if (ws_size < need) return;

  // 0. convert x, Wi to bf16
  f32_to_bf16_kernel<<<(int)((long)ROWS*EMB/8/256), 256, 0, stream>>>(x, xb, (long)ROWS*EMB);
  f32_to_bf16_kernel<<<(int)((long)PROJD*EMB/8/256), 256, 0, stream>>>(Wi, Wib, (long)PROJD*EMB);
  // 1. proj = x @ Wi^T  (MFMA, M=4096, N=8512, K=2048) -> bf16
  gemm_mfma_bt<ushort><<<dim3((PROJD+127)/128, ROWS/128), 256, 0, stream>>>(
      xb, EMB, Wib, EMB, projb, PROJD, PROJD, EMB);
  // 2. causal depthwise conv + silu -> bf16 (overwrites xb/Wib: dead)
  conv_silu_kernel<<<(int)(((long)ROWS*(CONVD/4)+255)/256), 256, 0, stream>>>(
      projb, cw, cb, convb);
  // 3. dt = softplus(...)
  dt_kernel<<<ROWS*NHEADS/256, 256, 0, stream>>>(projb, dt_bias, dtb);
  // 4. chunk cumsums of A*dt
  acum_kernel<<<(NBATCH*NCH*NHEADS+255)/256, 256, 0, stream>>>(dtb, A_log, acum);
  // 5. G[l,s] = sum_n C[l,n]*B[s,n] per (b,chunk)
  gemm_bnt<ushort,ushort,float><<<dim3(1,1,NBATCH*NCH), 256, 0, stream>>>(
      convb + INTER + STATE, CONVD, (long)CHUNK*CONVD,
      convb + INTER,         CONVD, (long)CHUNK*CONVD,
      Gb, CHUNK, (long)CHUNK*CHUNK, CHUNK, CHUNK, CHUNK);
  // 6. per-chunk end states -> bf16
  states_kernel<<<dim3(NHEADS, NCH, NBATCH), 256, 0, stream>>>(convb, dtb, acum, st);
  // 7. sequential inter-chunk scan (in place)
  scan_kernel<<<NBATCH*NHEADS, 256, 0, stream>>>(st, acum);
  // 8. y = Y_diag + Y_off + D*hid  (MFMA; into proj cols [INTER, 2*INTER))
  y_mfma_kernel<<<dim3(NHEADS, NCH*2, NBATCH), 256, 0, stream>>>(
      convb, dtb, acum, Gb, st, Dp, projb);
  // 9. gating + RMSNorm (in place, bf16)
  gate_norm_kernel<<<ROWS, 256, 0, stream>>>(projb, nw);
  // 9.5 convert Wo to bf16 (overlays dead convb — after y)
  f32_to_bf16_kernel<<<(int)((long)EMB*INTER/8/256), 256, 0, stream>>>(Wo, Wob, (long)EMB*INTER);
  // 10. out = yn @ Wo^T  (MFMA, M=4096, N=2048, K=4096) -> f32
  gemm_mfma_bt<float><<<dim3(EMB/128, ROWS/128), 256, 0, stream>>>(
      projb + INTER, PROJD, Wob, INTER, out, EMB, EMB, INTER);
}

// Round 6
// 661.760 us; speedup vs baseline: 5.0281x; 1.2198x over previous
//
#include <hip/hip_runtime.h>
#include <math.h>

#define NHEADS   64
#define EMB      2048
#define STATE    128
#define KCONV    4
#define HEAD_DIM 64
#define CHUNK    128
#define SEQL     2048
#define NBATCH   2
#define NCH      (SEQL/CHUNK)          // 16
#define INTER    (NHEADS*HEAD_DIM)     // 4096
#define CONVD    (INTER + 2*STATE)     // 4352
#define PROJD    (INTER + CONVD + NHEADS) // 8512
#define ROWS     (NBATCH*SEQL)         // 4096
#define EPSV     1e-6f

__device__ __forceinline__ float sigmoidf_(float x){ return 1.f/(1.f+__expf(-x)); }

// ---- bf16 (stored as ushort) helpers, f32 math everywhere -----------------
__device__ __forceinline__ float b2f(ushort u){
  union{float f; unsigned u;} x; x.u = ((unsigned)u)<<16; return x.f;
}
__device__ __forceinline__ ushort f2b(float f){
  union{float f; unsigned u;} x; x.f=f;
  unsigned r = x.u + 0x7FFFu + ((x.u>>16)&1u);
  return (ushort)(r>>16);
}
__device__ __forceinline__ float4 ld4(const float* p){ return *(const float4*)p; }
__device__ __forceinline__ float4 ld4(const ushort* p){
  ushort4 v = *(const ushort4*)p;
  return make_float4(b2f(v.x),b2f(v.y),b2f(v.z),b2f(v.w));
}
__device__ __forceinline__ void st4(float* p, float4 v){ *(float4*)p = v; }
__device__ __forceinline__ void st4(ushort* p, float4 v){
  ushort4 o; o.x=f2b(v.x); o.y=f2b(v.y); o.z=f2b(v.z); o.w=f2b(v.w);
  *(ushort4*)p = o;
}
__device__ __forceinline__ void stc(float* p, float v){ *p = v; }
__device__ __forceinline__ void stc(ushort* p, float v){ *p = f2b(v); }

// ---------------------------------------------------------------------------
// f32 -> bf16 bulk convert (n multiple of 8)
// ---------------------------------------------------------------------------
__global__ __launch_bounds__(256) void f32_to_bf16_kernel(
    const float* __restrict__ in, ushort* __restrict__ out, long n)
{
  long i = ((long)blockIdx.x*256 + threadIdx.x) * 8;
  if (i >= n) return;
  float4 a = *(const float4*)(in + i);
  float4 b = *(const float4*)(in + i + 4);
  st4(out + i, a);
  st4(out + i + 4, b);
}

// ---------------------------------------------------------------------------
// MFMA bf16 NT GEMM (m97 structure): C[m,n] = sum_k A[m,k]*B[n,k]
// 128x128 tile, BK=32, 256 threads = 4 waves. XCD-aware tile swizzle (T1).
// ---------------------------------------------------------------------------
typedef __attribute__((ext_vector_type(8))) short short8v;   // 8 bf16 = 4 VGPR
typedef __attribute__((ext_vector_type(4))) float float4v;

#define GLL16(g, l) __builtin_amdgcn_global_load_lds( \
    (const __attribute__((address_space(1))) void*)(g), \
    (__attribute__((address_space(3))) void*)(l), 16, 0, 0)

template<typename TC>
__global__ __launch_bounds__(256) void gemm_mfma_bt(
    const ushort* __restrict__ A, int lda,
    const ushort* __restrict__ B, int ldb,
    TC* __restrict__ C, int ldc,
    int N, int K)
{
  __shared__ ushort As[128*32];
  __shared__ ushort Bs[128*32];
  const int t = threadIdx.x;
  const int lt = t & 63, w = t >> 6;
  const int wr = w >> 1, wc = w & 1;

  // XCD-aware bijective swizzle: dispatch id -> tile id (contiguous per XCD)
  const int nwg = gridDim.x * gridDim.y;
  int orig = blockIdx.x + gridDim.x * blockIdx.y;
  int tile = orig;
  if ((nwg & 7) == 0) tile = (orig & 7) * (nwg >> 3) + (orig >> 3);
  const int m0 = (tile / gridDim.x) * 128;
  const int n0 = (tile % gridDim.x) * 128;

  float4v acc[4][4];
  #pragma unroll
  for (int i=0;i<4;++i)
    #pragma unroll
    for (int j=0;j<4;++j) acc[i][j] = float4v{0.f,0.f,0.f,0.f};

  const int srow = t >> 2;            // 0..63
  const int scol = (t & 3) * 8;       // k element offset of 16B chunk
  const int bn0 = min(n0 + srow, N-1);
  const int bn1 = min(n0 + 64 + srow, N-1);
  const long aoff0 = (long)(m0 + srow) * lda + scol;
  const long aoff1 = (long)(m0 + 64 + srow) * lda + scol;
  const long boff0 = (long)bn0 * ldb + scol;
  const long boff1 = (long)bn1 * ldb + scol;
  const int lr = lt & 15, lk = (lt >> 4) * 8;

  for (int k0 = 0; k0 < K; k0 += 32) {
    GLL16(A + aoff0 + k0, As + t*8);
    GLL16(A + aoff1 + k0, As + 2048 + t*8);
    GLL16(B + boff0 + k0, Bs + t*8);
    GLL16(B + boff1 + k0, Bs + 2048 + t*8);
    __syncthreads();
    short8v af[4], bf[4];
    #pragma unroll
    for (int i = 0; i < 4; ++i) {
      af[i] = *(const short8v*)(As + (wr*64 + i*16 + lr)*32 + lk);
      bf[i] = *(const short8v*)(Bs + (wc*64 + i*16 + lr)*32 + lk);
    }
    #pragma unroll
    for (int i = 0; i < 4; ++i)
      #pragma unroll
      for (int j = 0; j < 4; ++j)
        acc[i][j] = __builtin_amdgcn_mfma_f32_16x16x32_bf16(af[i], bf[j], acc[i][j], 0, 0, 0);
    __syncthreads();
  }

  const int cr = (lt >> 4) * 4;   // C/D: col=lane&15, row=(lane>>4)*4+reg (m89)
  const int cc = lt & 15;
  #pragma unroll
  for (int i = 0; i < 4; ++i) {
    #pragma unroll
    for (int j = 0; j < 4; ++j) {
      int col = n0 + wc*64 + j*16 + cc;
      if (col < N) {
        #pragma unroll
        for (int r = 0; r < 4; ++r) {
          int row = m0 + wr*64 + i*16 + cr + r;
          stc(C + (long)row*ldc + col, acc[i][j][r]);
        }
      }
    }
  }
}

// ---------------------------------------------------------------------------
// SIMT NT GEMM (kept for the small per-chunk G = C B^T, 32 blocks of 128^3)
// ---------------------------------------------------------------------------
#define BM 128
#define BN 128
#define BKK 16

template<typename TA, typename TB, typename TC>
__global__ __launch_bounds__(256) void gemm_bnt(
    const TA* __restrict__ A, int lda, long sA,
    const TB* __restrict__ B, int ldb, long sB,
    TC* __restrict__ C, int ldc, long sC,
    int M, int N, int K)
{
  A += (long)blockIdx.z * sA;
  B += (long)blockIdx.z * sB;
  C += (long)blockIdx.z * sC;
  const int n0 = blockIdx.x * BN;
  const int m0 = blockIdx.y * BM;
  __shared__ float As[BKK][BM+4];
  __shared__ float Bs[BKK][BN+4];
  const int t = threadIdx.x;
  const int tx = t & 15, ty = t >> 4;
  float acc[8][8];
  #pragma unroll
  for (int i=0;i<8;++i)
    #pragma unroll
    for (int j=0;j<8;++j) acc[i][j]=0.f;

  for (int k0 = 0; k0 < K; k0 += BKK) {
    #pragma unroll
    for (int i = 0; i < 2; ++i) {
      int f = t + i*256;
      int row = f >> 2, kq = (f & 3) << 2;
      float4 v = ld4(A + (long)(m0+row)*lda + (k0 + kq));
      As[kq+0][row]=v.x; As[kq+1][row]=v.y; As[kq+2][row]=v.z; As[kq+3][row]=v.w;
      int gn = n0 + row;
      float4 w = make_float4(0.f,0.f,0.f,0.f);
      if (gn < N) w = ld4(B + (long)gn*ldb + (k0 + kq));
      Bs[kq+0][row]=w.x; Bs[kq+1][row]=w.y; Bs[kq+2][row]=w.z; Bs[kq+3][row]=w.w;
    }
    __syncthreads();
    #pragma unroll
    for (int k = 0; k < BKK; ++k) {
      float a[8], b[8];
      *(float4*)&a[0] = *(const float4*)&As[k][ty*8];
      *(float4*)&a[4] = *(const float4*)&As[k][ty*8+4];
      *(float4*)&b[0] = *(const float4*)&Bs[k][tx*8];
      *(float4*)&b[4] = *(const float4*)&Bs[k][tx*8+4];
      #pragma unroll
      for (int i = 0; i < 8; ++i)
        #pragma unroll
        for (int j = 0; j < 8; ++j)
          acc[i][j] = fmaf(a[i], b[j], acc[i][j]);
    }
    __syncthreads();
  }
  #pragma unroll
  for (int i = 0; i < 8; ++i) {
    int gm = m0 + ty*8 + i;
    #pragma unroll
    for (int j = 0; j < 8; j += 4) {
      int gn = n0 + tx*8 + j;
      if (gn < N)
        st4(C + (long)gm*ldc + gn,
            make_float4(acc[i][j],acc[i][j+1],acc[i][j+2],acc[i][j+3]));
    }
  }
}

// ---------------------------------------------------------------------------
// Depthwise causal conv (K=4) + bias + SiLU over proj cols [INTER, INTER+CONVD)
// ---------------------------------------------------------------------------
__global__ __launch_bounds__(256) void conv_silu_kernel(
    const ushort* __restrict__ proj, const float* __restrict__ cw,
    const float* __restrict__ cb, ushort* __restrict__ out)
{
  const int C4 = CONVD/4;
  long idx = (long)blockIdx.x*256 + threadIdx.x;
  if (idx >= (long)ROWS*C4) return;
  int r = (int)(idx / C4);
  int c = (int)(idx % C4) * 4;
  int tt = r & (SEQL-1);
  float4 bv = *(const float4*)(cb + c);
  float acc0=bv.x, acc1=bv.y, acc2=bv.z, acc3=bv.w;
  float4 w0 = *(const float4*)(cw + (c+0)*KCONV);
  float4 w1 = *(const float4*)(cw + (c+1)*KCONV);
  float4 w2 = *(const float4*)(cw + (c+2)*KCONV);
  float4 w3 = *(const float4*)(cw + (c+3)*KCONV);
  const float wj0[4] = {w0.x,w0.y,w0.z,w0.w};
  const float wj1[4] = {w1.x,w1.y,w1.z,w1.w};
  const float wj2[4] = {w2.x,w2.y,w2.z,w2.w};
  const float wj3[4] = {w3.x,w3.y,w3.z,w3.w};
  #pragma unroll
  for (int j = 0; j < KCONV; ++j) {
    int tr = tt - (KCONV-1) + j;
    if (tr >= 0) {
      float4 v = ld4(proj + (long)(r - (KCONV-1) + j)*PROJD + INTER + c);
      acc0 = fmaf(v.x, wj0[j], acc0);
      acc1 = fmaf(v.y, wj1[j], acc1);
      acc2 = fmaf(v.z, wj2[j], acc2);
      acc3 = fmaf(v.w, wj3[j], acc3);
    }
  }
  float4 o;
  o.x = acc0 * sigmoidf_(acc0);
  o.y = acc1 * sigmoidf_(acc1);
  o.z = acc2 * sigmoidf_(acc2);
  o.w = acc3 * sigmoidf_(acc3);
  st4(out + (long)r*CONVD + c, o);
}

// dt = softplus(dt_raw + bias)
__global__ void dt_kernel(const ushort* __restrict__ proj,
                          const float* __restrict__ dt_bias,
                          float* __restrict__ dtb)
{
  int idx = blockIdx.x*256 + threadIdx.x;
  if (idx >= ROWS*NHEADS) return;
  int r = idx >> 6, h = idx & 63;
  float xv = b2f(proj[(long)r*PROJD + INTER + CONVD + h]) + dt_bias[h];
  dtb[idx] = fmaxf(xv, 0.f) + __logf(1.f + __expf(-fabsf(xv)));
}

// per-(b,chunk,head) inclusive cumsum of A*dt over the chunk
__global__ void acum_kernel(const float* __restrict__ dtb,
                            const float* __restrict__ A_log,
                            float* __restrict__ acum)
{
  int idx = blockIdx.x*256 + threadIdx.x;
  if (idx >= NBATCH*NCH*NHEADS) return;
  int h = idx & 63, bc = idx >> 6;
  float Ah = -__expf(A_log[h]);
  const float* d = dtb + (long)bc*CHUNK*NHEADS + h;
  float* o = acum + (long)idx*CHUNK;
  float acc = 0.f;
  for (int l = 0; l < CHUNK; ++l) { acc = fmaf(Ah, d[l*NHEADS], acc); o[l] = acc; }
}

// ---------------------------------------------------------------------------
// MFMA states kernel: states[p,n] = sum_l (w[l]*hid[l,p]) * B[l,n]
// per (h,c,b). M=64(p), N=128(n), K=128(l). Weighted-hid operand split hi/lo
// bf16 (exact to ~2^-17 — no added rounding vs f32 path). 4 waves: wave w owns
// p-rows w*16..w*16+15, all 8 n-frags.
// ---------------------------------------------------------------------------
__global__ __launch_bounds__(256) void states_mfma_kernel(
    const ushort* __restrict__ conv, const float* __restrict__ dtb,
    const float* __restrict__ acum, ushort* __restrict__ states)
{
  const int h = blockIdx.x, c = blockIdx.y, b = blockIdx.z;
  const int bc = b*NCH + c;
  const long r0 = (long)bc*CHUNK;
  __shared__ ushort Ahi[64][136];   // (w*hid)^T hi: [p][l]
  __shared__ ushort Alo[64][136];   // lo residual
  __shared__ ushort Bt[128][136];   // B^T: [n][l]
  __shared__ float arow[CHUNK];
  __shared__ float wrow[CHUNK];
  const int t = threadIdx.x;
  const int lt = t & 63, w = t >> 6;
  const int lr = lt & 15, lk = (lt >> 4) * 8;

  if (t < CHUNK) arow[t] = acum[((long)bc*NHEADS + h)*CHUNK + t];
  __syncthreads();
  if (t < CHUNK) wrow[t] = dtb[(r0 + t)*NHEADS + h] * __expf(arow[CHUNK-1] - arow[t]);
  __syncthreads();

  for (int i = t; i < CHUNK*HEAD_DIM/8; i += 256) {   // 1024: 4 iters
    int l = i >> 3, p0 = (i & 7) * 8;
    short8v v = *(const short8v*)(conv + (r0+l)*CONVD + h*HEAD_DIM + p0);
    float wl = wrow[l];
    #pragma unroll
    for (int j = 0; j < 8; ++j) {
      float f = b2f((ushort)v[j]) * wl;
      ushort hb = f2b(f);
      Ahi[p0+j][l] = hb;
      Alo[p0+j][l] = f2b(f - b2f(hb));
    }
  }
  for (int i = t; i < CHUNK*STATE/8; i += 256) {      // 2048: 8 iters
    int l = i >> 4, n0 = (i & 15) * 8;
    short8v v = *(const short8v*)(conv + (r0+l)*CONVD + INTER + n0);
    #pragma unroll
    for (int j = 0; j < 8; ++j) Bt[n0+j][l] = (ushort)v[j];
  }
  __syncthreads();

  float4v acc[8];
  #pragma unroll
  for (int j = 0; j < 8; ++j) acc[j] = float4v{0,0,0,0};
  #pragma unroll
  for (int kk = 0; kk < 4; ++kk) {
    short8v ahi = *(const short8v*)&Ahi[w*16 + lr][kk*32 + lk];
    short8v alo = *(const short8v*)&Alo[w*16 + lr][kk*32 + lk];
    #pragma unroll
    for (int nj = 0; nj < 8; ++nj) {
      short8v bv = *(const short8v*)&Bt[nj*16 + lr][kk*32 + lk];
      acc[nj] = __builtin_amdgcn_mfma_f32_16x16x32_bf16(ahi, bv, acc[nj], 0, 0, 0);
      acc[nj] = __builtin_amdgcn_mfma_f32_16x16x32_bf16(alo, bv, acc[nj], 0, 0, 0);
    }
  }
  ushort* so = states + ((long)bc*NHEADS + h)*HEAD_DIM*STATE;
  const int cr = (lt >> 4) * 4, cc = lt & 15;
  #pragma unroll
  for (int nj = 0; nj < 8; ++nj)
    #pragma unroll
    for (int r = 0; r < 4; ++r)
      so[(w*16 + cr + r)*STATE + nj*16 + cc] = f2b(acc[nj][r]);
}

// in-place inter-chunk scan: states[c] <- init_state entering chunk c
__global__ __launch_bounds__(256) void scan_kernel(
    ushort* __restrict__ states, const float* __restrict__ acum)
{
  const int bh = blockIdx.x;          // b*NHEADS + h
  const int b = bh >> 6, h = bh & 63;
  const int t = threadIdx.x;
  float acc[32];
  #pragma unroll
  for (int i=0;i<32;++i) acc[i]=0.f;
  for (int c = 0; c < NCH; ++c) {
    const long bch = ((long)(b*NCH + c)*NHEADS + h);
    float lam = __expf(acum[bch*CHUNK + CHUNK-1]);
    ushort* sb = states + bch*HEAD_DIM*STATE;
    #pragma unroll
    for (int i = 0; i < 32; ++i) {
      float v = b2f(sb[t + i*256]);
      sb[t + i*256] = f2b(acc[i]);
      acc[i] = fmaf(acc[i], lam, v);
    }
  }
}

// ---------------------------------------------------------------------------
// MFMA y-kernel (verified R5). This round: expf -> __expf only.
// ---------------------------------------------------------------------------
__global__ __launch_bounds__(256) void y_mfma_kernel(
    const ushort* __restrict__ conv, const float* __restrict__ dtb,
    const float* __restrict__ acum, const float* __restrict__ G,
    const ushort* __restrict__ states, const float* __restrict__ Dp,
    ushort* __restrict__ proj)
{
  const int h = blockIdx.x;
  const int c = blockIdx.y >> 1, mh = blockIdx.y & 1;
  const int b = blockIdx.z;
  const int bc = b*NCH + c;
  const int mbase = mh * 64;
  const long r0 = (long)bc*CHUNK;

  __shared__ float  Af[64][132];     // W (f32), then C (f32 from bf16, exact)
  __shared__ ushort B0[64][136];     // hid^T: B0[p][s], s over FULL chunk
  __shared__ ushort B1[64][136];     // init:  B1[p][n]
  __shared__ float arow[CHUNK];
  __shared__ float dtr[CHUNK];
  __shared__ float el[64];

  const int t = threadIdx.x;
  const int lt = t & 63, w = t >> 6;
  const int lr = lt & 15, lk = (lt >> 4) * 8;

  if (t < CHUNK) {
    arow[t] = acum[((long)bc*NHEADS + h)*CHUNK + t];
    dtr[t]  = dtb[(r0 + t)*NHEADS + h];
  }
  __syncthreads();

  if (t < 64) el[t] = __expf(arow[mbase + t]);
  for (int i = t; i < CHUNK*HEAD_DIM/8; i += 256) {
    int s = i >> 3, p0 = (i & 7) * 8;
    short8v v = *(const short8v*)(conv + (r0+s)*CONVD + h*HEAD_DIM + p0);
    #pragma unroll
    for (int j = 0; j < 8; ++j) B0[p0+j][s] = (ushort)v[j];
  }
  {
    const ushort* stb = states + ((long)bc*NHEADS + h)*HEAD_DIM*STATE;
    for (int i = t; i < HEAD_DIM*STATE/8; i += 256) {
      int p = i >> 4, n0 = (i & 15) * 8;
      *(short8v*)&B1[p][n0] = *(const short8v*)(stb + p*STATE + n0);
    }
  }
  {
    const float* Gb = G + (long)bc*CHUNK*CHUNK;
    for (int i = t; i < 64*CHUNK; i += 256) {
      int ll = i >> 7, s = i & 127;
      int l = mbase + ll;
      float wv = 0.f;
      if (s <= l) wv = Gb[l*CHUNK + s] * __expf(arow[l] - arow[s]) * dtr[s];
      Af[ll][s] = wv;
    }
  }
  __syncthreads();

  float4v acc1[4], acc2[4];
  #pragma unroll
  for (int j = 0; j < 4; ++j) { acc1[j] = float4v{0,0,0,0}; acc2[j] = float4v{0,0,0,0}; }

  // mm1: Y_diag, W split hi/lo
  #pragma unroll
  for (int kk = 0; kk < 4; ++kk) {
    const float* ap = &Af[w*16 + lr][kk*32 + lk];
    float a8[8];
    *(float4*)&a8[0] = *(const float4*)ap;
    *(float4*)&a8[4] = *(const float4*)(ap + 4);
    short8v ahi, alo;
    #pragma unroll
    for (int e = 0; e < 8; ++e) {
      ushort hb = f2b(a8[e]);
      float rem = a8[e] - b2f(hb);
      ahi[e] = (short)hb;
      alo[e] = (short)f2b(rem);
    }
    #pragma unroll
    for (int nj = 0; nj < 4; ++nj) {
      short8v bfv = *(const short8v*)&B0[nj*16 + lr][kk*32 + lk];
      acc1[nj] = __builtin_amdgcn_mfma_f32_16x16x32_bf16(ahi, bfv, acc1[nj], 0, 0, 0);
      acc1[nj] = __builtin_amdgcn_mfma_f32_16x16x32_bf16(alo, bfv, acc1[nj], 0, 0, 0);
    }
  }
  __syncthreads();

  for (int i = t; i < 64*STATE; i += 256) {
    int ll = i >> 7, n = i & 127;
    Af[ll][n] = b2f(conv[(r0 + mbase + ll)*CONVD + INTER + STATE + n]);
  }
  __syncthreads();

  // mm2: C @ init^T (exact)
  #pragma unroll
  for (int kk = 0; kk < 4; ++kk) {
    const float* ap = &Af[w*16 + lr][kk*32 + lk];
    float a8[8];
    *(float4*)&a8[0] = *(const float4*)ap;
    *(float4*)&a8[4] = *(const float4*)(ap + 4);
    short8v ahi;
    #pragma unroll
    for (int e = 0; e < 8; ++e) ahi[e] = (short)f2b(a8[e]);
    #pragma unroll
    for (int nj = 0; nj < 4; ++nj) {
      short8v bfv = *(const short8v*)&B1[nj*16 + lr][kk*32 + lk];
      acc2[nj] = __builtin_amdgcn_mfma_f32_16x16x32_bf16(ahi, bfv, acc2[nj], 0, 0, 0);
    }
  }

  const float Dh = Dp[h];
  const int cr = (lt >> 4) * 4, cc = lt & 15;
  #pragma unroll
  for (int nj = 0; nj < 4; ++nj) {
    int p = nj*16 + cc;
    #pragma unroll
    for (int r = 0; r < 4; ++r) {
      int ll = w*16 + cr + r;
      float hid_raw = b2f(B0[p][mbase + ll]);
      float yv = acc1[nj][r] + el[ll]*acc2[nj][r] + Dh*hid_raw;
      proj[(r0 + mbase + ll)*PROJD + INTER + h*HEAD_DIM + p] = f2b(yv);
    }
  }
}

// yg = y*silu(gate); rmsnorm; write yn back in place (per row)
__global__ __launch_bounds__(256) void gate_norm_kernel(
    ushort* __restrict__ proj, const float* __restrict__ nw)
{
  const int r = blockIdx.x;
  const int t = threadIdx.x;
  __shared__ float red[256];
  ushort* gate = proj + (long)r*PROJD;
  ushort* y = gate + INTER;
  float vals[16];
  float ss = 0.f;
  #pragma unroll
  for (int k = 0; k < 4; ++k) {
    int j = (t + k*256) * 4;
    float4 g = ld4(gate + j);
    float4 yv = ld4(y + j);
    float v0 = yv.x * g.x * sigmoidf_(g.x);
    float v1 = yv.y * g.y * sigmoidf_(g.y);
    float v2 = yv.z * g.z * sigmoidf_(g.z);
    float v3 = yv.w * g.w * sigmoidf_(g.w);
    vals[k*4+0]=v0; vals[k*4+1]=v1; vals[k*4+2]=v2; vals[k*4+3]=v3;
    ss += v0*v0 + v1*v1 + v2*v2 + v3*v3;
  }
  red[t] = ss;
  __syncthreads();
  for (int sft = 128; sft > 0; sft >>= 1) {
    if (t < sft) red[t] += red[t+sft];
    __syncthreads();
  }
  float scale = rsqrtf(red[0] / (float)INTER + EPSV);
  #pragma unroll
  for (int k = 0; k < 4; ++k) {
    int j = (t + k*256) * 4;
    float4 w = *(const float4*)(nw + j);
    st4(y + j, make_float4(vals[k*4+0]*scale*w.x, vals[k*4+1]*scale*w.y,
                           vals[k*4+2]*scale*w.z, vals[k*4+3]*scale*w.w));
  }
}

extern "C" void kernel_launch(void* const* d_in, const int* in_sizes, int n_in,
                              void* d_out, int out_size, void* d_ws, size_t ws_size,
                              hipStream_t stream) {
  const float* x       = (const float*)d_in[0];
  const float* Wi      = (const float*)d_in[1];
  const float* cw      = (const float*)d_in[2];
  const float* cb      = (const float*)d_in[3];
  const float* dt_bias = (const float*)d_in[4];
  const float* A_log   = (const float*)d_in[5];
  const float* Dp      = (const float*)d_in[6];
  const float* nw      = (const float*)d_in[7];
  const float* Wo      = (const float*)d_in[8];
  float* out = (float*)d_out;

  // ---- workspace layout: identical 143,130,624-byte footprint as R2 -------
  ushort* projb = (ushort*)d_ws;
  ushort* R     = projb + (size_t)ROWS*PROJD;
  ushort* xb    = R;
  ushort* Wib   = R + (size_t)ROWS*EMB;
  ushort* Wob   = R;
  ushort* convb = R;
  float*  dtb   = (float*)(convb + (size_t)ROWS*CONVD);
  float*  acum  = dtb  + (size_t)ROWS*NHEADS;
  float*  Gb    = acum + (size_t)NBATCH*NCH*NHEADS*CHUNK;
  ushort* st    = (ushort*)(Gb + (size_t)NBATCH*NCH*CHUNK*CHUNK);

  size_t need = (size_t)ROWS*PROJD*2 + (size_t)ROWS*CONVD*2
              + (size_t)ROWS*NHEADS*4 + (size_t)NBATCH*NCH*NHEADS*CHUNK*4
              + (size_t)NBATCH*NCH*CHUNK*CHUNK*4
              + (size_t)NBATCH*NCH*NHEADS*HEAD_DIM*STATE*2;
  if (ws_size < need) return;

  // 0. convert x, Wi to bf16
  f32_to_bf16_kernel<<<(int)((long)ROWS*EMB/8/256), 256, 0, stream>>>(x, xb, (long)ROWS*EMB);
  f32_to_bf16_kernel<<<(int)((long)PROJD*EMB/8/256), 256, 0, stream>>>(Wi, Wib, (long)PROJD*EMB);
  // 1. proj = x @ Wi^T  (MFMA, M=4096, N=8512, K=2048) -> bf16
  gemm_mfma_bt<ushort><<<dim3((PROJD+127)/128, ROWS/128), 256, 0, stream>>>(
      xb, EMB, Wib, EMB, projb, PROJD, PROJD, EMB);
  // 2. causal depthwise conv + silu -> bf16 (overwrites xb/Wib: dead)
  conv_silu_kernel<<<(int)(((long)ROWS*(CONVD/4)+255)/256), 256, 0, stream>>>(
      projb, cw, cb, convb);
  // 3. dt = softplus(...)
  dt_kernel<<<ROWS*NHEADS/256, 256, 0, stream>>>(projb, dt_bias, dtb);
  // 4. chunk cumsums of A*dt
  acum_kernel<<<(NBATCH*NCH*NHEADS+255)/256, 256, 0, stream>>>(dtb, A_log, acum);
  // 5. G[l,s] = sum_n C[l,n]*B[s,n] per (b,chunk)
  gemm_bnt<ushort,ushort,float><<<dim3(1,1,NBATCH*NCH), 256, 0, stream>>>(
      convb + INTER + STATE, CONVD, (long)CHUNK*CONVD,
      convb + INTER,         CONVD, (long)CHUNK*CONVD,
      Gb, CHUNK, (long)CHUNK*CHUNK, CHUNK, CHUNK, CHUNK);
  // 6. per-chunk end states -> bf16 (MFMA)
  states_mfma_kernel<<<dim3(NHEADS, NCH, NBATCH), 256, 0, stream>>>(convb, dtb, acum, st);
  // 7. sequential inter-chunk scan (in place)
  scan_kernel<<<NBATCH*NHEADS, 256, 0, stream>>>(st, acum);
  // 8. y = Y_diag + Y_off + D*hid  (MFMA; into proj cols [INTER, 2*INTER))
  y_mfma_kernel<<<dim3(NHEADS, NCH*2, NBATCH), 256, 0, stream>>>(
      convb, dtb, acum, Gb, st, Dp, projb);
  // 9. gating + RMSNorm (in place, bf16)
  gate_norm_kernel<<<ROWS, 256, 0, stream>>>(projb, nw);
  // 9.5 convert Wo to bf16 (overlays dead convb — after y)
  f32_to_bf16_kernel<<<(int)((long)EMB*INTER/8/256), 256, 0, stream>>>(Wo, Wob, (long)EMB*INTER);
  // 10. out = yn @ Wo^T  (MFMA, M=4096, N=2048, K=4096) -> f32
  gemm_mfma_bt<float><<<dim3(EMB/128, ROWS/128), 256, 0, stream>>>(
      projb + INTER, PROJD, Wob, INTER, out, EMB, EMB, INTER);
}